// Round 3
// baseline (4916.449 us; speedup 1.0000x reference)
//
#include <hip/hip_runtime.h>
#include <hip/hip_bf16.h>
#include <math.h>

using bf16 = __hip_bfloat16;
typedef short s16x8 __attribute__((ext_vector_type(8)));
typedef float f32x4 __attribute__((ext_vector_type(4)));

#define DEVI __device__ __forceinline__

static constexpr int NB    = 4;
static constexpr int NTOK  = 1024;
static constexpr int DIM   = 768;
static constexpr int NH    = 12;
static constexpr int MLPD  = 3072;
static constexpr int NLAYER= 4;
static constexpr int NIMG  = 4;
static constexpr int NCLS  = 1000;
static constexpr int MR    = NB * NTOK;   // 4096 rows

DEVI float b2f(bf16 v){ return __bfloat162float(v); }
DEVI bf16  f2b(float v){ return __float2bfloat16(v); }

DEVI void async16(const void* g, void* l) {
  __builtin_amdgcn_global_load_lds((const __attribute__((address_space(1))) void*)g,
                                   (__attribute__((address_space(3))) void*)l, 16, 0, 0);
}

DEVI f32x4 mfma16(s16x8 a, s16x8 b, f32x4 c) {
  return __builtin_amdgcn_mfma_f32_16x16x32_bf16(a, b, c, 0, 0, 0);
}

DEVI float block_sum(float v, float* scratch, int tid) {
  #pragma unroll
  for (int o = 32; o >= 1; o >>= 1) v += __shfl_xor(v, o);
  __syncthreads();
  if ((tid & 63) == 0) scratch[tid >> 6] = v;
  __syncthreads();
  return scratch[0] + scratch[1] + scratch[2] + scratch[3];
}

DEVI float block_max(float v, float* scratch, int tid) {
  #pragma unroll
  for (int o = 32; o >= 1; o >>= 1) v = fmaxf(v, __shfl_xor(v, o));
  __syncthreads();
  if ((tid & 63) == 0) scratch[tid >> 6] = v;
  __syncthreads();
  return fmaxf(fmaxf(scratch[0], scratch[1]), fmaxf(scratch[2], scratch[3]));
}

// ---------------------------------------------------------------- transpose + f32->bf16 convert
struct bh4 { bf16 a, b, c, d; };
struct TEntry { const float* src; bf16* dst; int R, C, tiles, tC; };
struct TDesc  { TEntry e[22]; };

__global__ __launch_bounds__(256) void transpose_kernel(TDesc D, int nent) {
  int bid = blockIdx.x, ei = 0;
  while (ei < nent - 1 && bid >= D.e[ei].tiles) { bid -= D.e[ei].tiles; ++ei; }
  const TEntry E = D.e[ei];
  const int tr = bid / E.tC, tc = bid % E.tC;
  __shared__ bf16 t[32][33];
  const int tid = threadIdx.x;
  const int lr = tid >> 3, lc = (tid & 7) * 4;
  const float* srow = E.src + (size_t)(tr*32 + lr)*E.C + tc*32 + lc;
  float4 v = *(const float4*)srow;
  t[lr][lc] = f2b(v.x); t[lr][lc+1] = f2b(v.y); t[lr][lc+2] = f2b(v.z); t[lr][lc+3] = f2b(v.w);
  __syncthreads();
  bh4 o;
  o.a = t[lc+0][lr]; o.b = t[lc+1][lr]; o.c = t[lc+2][lr]; o.d = t[lc+3][lr];
  *(bh4*)(E.dst + (size_t)(tc*32 + lr)*E.R + tr*32 + lc) = o;
}

// ---------------------------------------------------------------- LayerNorm (768 cols), f32 in, bf16 out
__global__ __launch_bounds__(256) void ln768_kernel(const float* __restrict__ in,
    const float* __restrict__ g, bf16* __restrict__ out)
{
  __shared__ float scratch[4];
  const int row = blockIdx.x, tid = threadIdx.x;
  const float* p = in + (size_t)row*768;
  const float v0 = p[tid], v1 = p[tid+256], v2 = p[tid+512];
  const float s  = block_sum(v0+v1+v2, scratch, tid);
  const float ss = block_sum(v0*v0+v1*v1+v2*v2, scratch, tid);
  const float mu = s * (1.0f/768.0f);
  const float var = ss * (1.0f/768.0f) - mu*mu;
  const float rstd = rsqrtf(var + 1e-5f);
  bf16* o = out + (size_t)row*768;
  o[tid]     = f2b((v0-mu)*rstd*g[tid]);
  o[tid+256] = f2b((v1-mu)*rstd*g[tid+256]);
  o[tid+512] = f2b((v2-mu)*rstd*g[tid+512]);
}

// LN + positional add (embed stage 2), f32 out
__global__ __launch_bounds__(256) void ln_pos_kernel(const float* __restrict__ in,
    const float* __restrict__ g, const float* __restrict__ pos_h, const float* __restrict__ pos_w,
    const int* __restrict__ ppos, float* __restrict__ out)
{
  __shared__ float scratch[4];
  const int row = blockIdx.x, tid = threadIdx.x;
  const float* p = in + (size_t)row*768;
  const float v0 = p[tid], v1 = p[tid+256], v2 = p[tid+512];
  const float s  = block_sum(v0+v1+v2, scratch, tid);
  const float ss = block_sum(v0*v0+v1*v1+v2*v2, scratch, tid);
  const float mu = s * (1.0f/768.0f);
  const float rstd = rsqrtf(ss*(1.0f/768.0f) - mu*mu + 1e-5f);
  const int p0 = ppos[row*2], p1 = ppos[row*2+1];
  const float* ph = pos_h + (size_t)p0*768;
  const float* pw = pos_w + (size_t)p1*768;
  float* o = out + (size_t)row*768;
  o[tid]     = (v0-mu)*rstd*g[tid]     + ph[tid]     + pw[tid];
  o[tid+256] = (v1-mu)*rstd*g[tid+256] + ph[tid+256] + pw[tid+256];
  o[tid+512] = (v2-mu)*rstd*g[tid+512] + ph[tid+512] + pw[tid+512];
}

// ---------------------------------------------------------------- GEMM (MFMA, m97-style)
// C[M,Nn] = A[M,K](bf16) @ W[K,Nn] given BT = W^T [Nn,K] row-major bf16.
template<int DO_BIAS, int DO_RES, int DO_GELU, int OUT_BF16>
__global__ __launch_bounds__(256)
void gemm_mfma(const bf16* __restrict__ A, const bf16* __restrict__ BT,
               const float* __restrict__ bias, float* __restrict__ Cf,
               bf16* __restrict__ Cb, int M, int Nn, int K)
{
  __shared__ bf16 As[128*32];
  __shared__ bf16 Bs[128*32];
  const int tid = threadIdx.x;
  const int wid = tid >> 6, lane = tid & 63;
  const int quad = lane >> 4, l15 = lane & 15;
  const int wy = wid >> 1, wx = wid & 1;
  const int m0 = blockIdx.y * 128, n0 = blockIdx.x * 128;
  const int ar = lane >> 2;            // row within 16-row staging group
  const int ac = (lane & 3) * 16;      // 16B chunk within 64B row

  f32x4 acc[4][4];
  #pragma unroll
  for (int i = 0; i < 4; ++i)
    #pragma unroll
    for (int j = 0; j < 4; ++j) acc[i][j] = (f32x4){0.f,0.f,0.f,0.f};

  for (int k0 = 0; k0 < K; k0 += 32) {
    #pragma unroll
    for (int c = 0; c < 2; ++c) {
      const int rb = wid*16 + c*64;
      async16((const char*)A  + ((size_t)(m0 + rb + ar)*K + k0)*2 + ac, (char*)As + rb*64);
      async16((const char*)BT + ((size_t)(n0 + rb + ar)*K + k0)*2 + ac, (char*)Bs + rb*64);
    }
    __syncthreads();
    s16x8 af[4], bfr[4];
    #pragma unroll
    for (int mt = 0; mt < 4; ++mt)
      af[mt] = *(const s16x8*)((const char*)As + (wy*64 + mt*16 + l15)*64 + quad*16);
    #pragma unroll
    for (int nt = 0; nt < 4; ++nt)
      bfr[nt] = *(const s16x8*)((const char*)Bs + (wx*64 + nt*16 + l15)*64 + quad*16);
    #pragma unroll
    for (int mt = 0; mt < 4; ++mt)
      #pragma unroll
      for (int nt = 0; nt < 4; ++nt)
        acc[mt][nt] = mfma16(af[mt], bfr[nt], acc[mt][nt]);
    __syncthreads();
  }

  #pragma unroll
  for (int nt = 0; nt < 4; ++nt) {
    const int col = n0 + wx*64 + nt*16 + l15;
    float bv = 0.f;
    if constexpr (DO_BIAS) bv = bias[col];
    #pragma unroll
    for (int mt = 0; mt < 4; ++mt) {
      #pragma unroll
      for (int r = 0; r < 4; ++r) {
        const int row = m0 + wy*64 + mt*16 + quad*4 + r;
        float v = acc[mt][nt][r];
        if constexpr (DO_BIAS) v += bv;
        if constexpr (DO_GELU) v = 0.5f*v*(1.0f + erff(v*0.70710678118654752f));
        const size_t idx = (size_t)row*Nn + col;
        if constexpr (OUT_BF16) Cb[idx] = f2b(v);
        else if constexpr (DO_RES) Cf[idx] += v;
        else Cf[idx] = v;
      }
    }
  }
}

// ---------------------------------------------------------------- qk rmsnorm (simple)
// one wave per (row, head). qkv: [MR][2304] f32. Qb/Kb: [b][h][n][64] bf16 (gamma folded),
// Vb: [b][h][n][64] bf16 raw.
__global__ __launch_bounds__(256) void rmsqkv_simple(const float* __restrict__ qkv,
    const float* __restrict__ qg, const float* __restrict__ kg,
    bf16* __restrict__ Qb, bf16* __restrict__ Kb, bf16* __restrict__ Vb)
{
  const int wid = threadIdx.x >> 6, lane = threadIdx.x & 63;
  const int widx = blockIdx.x*4 + wid;          // (row, h) pair
  const int row = widx / NH, h = widx % NH;
  const int b = row >> 10, n = row & 1023;
  const int bh = b*NH + h;
  const size_t base = (size_t)row*2304 + h*64 + lane;
  const float q = qkv[base];
  const float k = qkv[base + 768];
  const float v = qkv[base + 1536];

  float sq = q*q, sk = k*k;
  #pragma unroll
  for (int o = 32; o >= 1; o >>= 1) { sq += __shfl_xor(sq, o); sk += __shfl_xor(sk, o); }
  const float rq = 8.0f / fmaxf(sqrtf(sq), 1e-12f);
  const float rk = 8.0f / fmaxf(sqrtf(sk), 1e-12f);
  const size_t orow = ((size_t)bh*NTOK + n)*64 + lane;
  Qb[orow] = f2b(q * rq * qg[h*64 + lane]);
  Kb[orow] = f2b(k * rk * kg[h*64 + lane]);
  Vb[orow] = f2b(v);
}

// ---------------------------------------------------------------- attention (simple, correct)
// one wave per q row. grid (NTOK/4, NH, NB).
__global__ __launch_bounds__(256) void attn_simple(const bf16* __restrict__ Qb,
    const bf16* __restrict__ Kb, const bf16* __restrict__ Vb, bf16* __restrict__ Ob,
    const int* __restrict__ ids, const int* __restrict__ lens)
{
  __shared__ float qsh[4][64];
  __shared__ float psh[4][NTOK];
  const int wid = threadIdx.x >> 6, lane = threadIdx.x & 63;
  const int n = blockIdx.x*4 + wid;
  const int h = blockIdx.y, b = blockIdx.z;
  const int bh = b*NH + h;
  const int len = lens[b];
  const int img = ids[b*NTOK + n];

  qsh[wid][lane] = b2f(Qb[((size_t)bh*NTOK + n)*64 + lane]);
  __syncthreads();

  float s[16];
  float mx = -3.0e38f;
  #pragma unroll 1
  for (int t = 0; t < 16; ++t) {
    const int j = t*64 + lane;
    float sv = -3.0e38f;
    if (j < len && ids[b*NTOK + j] == img) {
      const bf16* kr = Kb + ((size_t)bh*NTOK + j)*64;
      float acc = 0.f;
      #pragma unroll
      for (int d = 0; d < 64; ++d) acc += qsh[wid][d] * b2f(kr[d]);
      sv = acc;
    }
    s[t] = sv;
    mx = fmaxf(mx, sv);
  }
  #pragma unroll
  for (int o = 32; o >= 1; o >>= 1) mx = fmaxf(mx, __shfl_xor(mx, o));

  float lsum = 0.f;
  #pragma unroll 1
  for (int t = 0; t < 16; ++t) {
    const float p = (s[t] > -1.0e38f) ? expf(s[t] - mx) : 0.0f;
    psh[wid][t*64 + lane] = p;
    lsum += p;
  }
  #pragma unroll
  for (int o = 32; o >= 1; o >>= 1) lsum += __shfl_xor(lsum, o);
  const float inv = lsum > 0.f ? 1.0f/lsum : 0.0f;
  __syncthreads();

  float acc = 0.f;     // lane = output dim d
  #pragma unroll 1
  for (int j = 0; j < NTOK; ++j) {
    const float p = psh[wid][j];          // wave-uniform broadcast
    if (p != 0.f)
      acc += p * b2f(Vb[((size_t)bh*NTOK + j)*64 + lane]);
  }
  Ob[((size_t)b*NTOK + n)*768 + h*64 + lane] = f2b(acc * inv);
}

// ---------------------------------------------------------------- pooling path
__global__ __launch_bounds__(256) void pool_q_kernel(const float* __restrict__ pool_q,
    const float* __restrict__ pool_ln_g, const float* __restrict__ pWq,
    const float* __restrict__ p_qn_g, float* __restrict__ qp)
{
  __shared__ float xn[768];
  __shared__ float scratch[4];
  __shared__ float qraw[64];
  const int h = blockIdx.x, tid = threadIdx.x;
  float v0 = pool_q[tid], v1 = pool_q[tid+256], v2 = pool_q[tid+512];
  const float s  = block_sum(v0+v1+v2, scratch, tid);
  const float ss = block_sum(v0*v0+v1*v1+v2*v2, scratch, tid);
  const float mu = s*(1.0f/768.0f);
  const float rstd = rsqrtf(ss*(1.0f/768.0f) - mu*mu + 1e-5f);
  xn[tid]     = (v0-mu)*rstd*pool_ln_g[tid];
  xn[tid+256] = (v1-mu)*rstd*pool_ln_g[tid+256];
  xn[tid+512] = (v2-mu)*rstd*pool_ln_g[tid+512];
  __syncthreads();
  const int d = tid >> 2, pp = tid & 3;
  const int col = h*64 + d;
  float acc = 0.f;
  for (int k = pp*192; k < (pp+1)*192; ++k) acc += xn[k]*pWq[(size_t)k*768 + col];
  acc += __shfl_xor(acc, 1); acc += __shfl_xor(acc, 2);
  if (pp == 0) qraw[d] = acc;
  __syncthreads();
  if (tid < 64) {
    const float q = qraw[tid];
    float sq = q*q;
    #pragma unroll
    for (int o = 32; o >= 1; o >>= 1) sq += __shfl_xor(sq, o);
    const float rn = 8.0f / fmaxf(sqrtf(sq), 1e-12f);
    qp[h*64 + tid] = q * rn * p_qn_g[h*64 + tid];
  }
}

__global__ __launch_bounds__(256) void pool_attn_kernel(const float* __restrict__ kvp,
    const float* __restrict__ qp, const float* __restrict__ kg,
    const int* __restrict__ ids, const int* __restrict__ lens, float* __restrict__ pooled)
{
  __shared__ float sp[1024];
  __shared__ float qg_s[64];
  __shared__ float scratch[4];
  __shared__ float outred[4][64];
  const int h = blockIdx.x, img = blockIdx.y, b = blockIdx.z;
  const int tid = threadIdx.x;
  const int len = lens[b];
  if (tid < 64) qg_s[tid] = qp[h*64 + tid] * kg[h*64 + tid];
  __syncthreads();

  float smax = -3.0e38f;
  for (int j = tid; j < 1024; j += 256) {
    float sv = -3.0e38f;
    if (j < len && ids[b*NTOK + j] == img) {
      const float* kr = kvp + (size_t)(b*NTOK + j)*1536 + h*64;
      float ssq = 0.f, dq = 0.f;
      #pragma unroll
      for (int dd = 0; dd < 64; dd += 4) {
        float4 k4 = *(const float4*)(kr + dd);
        ssq += k4.x*k4.x + k4.y*k4.y + k4.z*k4.z + k4.w*k4.w;
        dq  += qg_s[dd]*k4.x + qg_s[dd+1]*k4.y + qg_s[dd+2]*k4.z + qg_s[dd+3]*k4.w;
      }
      const float rn = 8.0f / fmaxf(sqrtf(ssq), 1e-12f);
      sv = dq * rn;
    }
    sp[j] = sv;
    smax = fmaxf(smax, sv);
  }
  const float M = block_max(smax, scratch, tid);
  float lsum = 0.f;
  for (int j = tid; j < 1024; j += 256) {
    const float p = (sp[j] > -1.0e38f) ? expf(sp[j] - M) : 0.0f;
    sp[j] = p;
    lsum += p;
  }
  const float L = block_sum(lsum, scratch, tid);
  const float invL = L > 0.f ? 1.0f / L : 0.0f;

  const int d = tid & 63, jg = tid >> 6;
  float acc = 0.f;
  for (int j = jg; j < 1024; j += 4) {
    const float p = sp[j];
    if (p > 0.f) acc += p * kvp[(size_t)(b*NTOK + j)*1536 + 768 + h*64 + d];
  }
  outred[jg][d] = acc;
  __syncthreads();
  if (tid < 64) {
    const float o = (outred[0][tid] + outred[1][tid] + outred[2][tid] + outred[3][tid]) * invL;
    pooled[((size_t)b*NIMG + img)*768 + h*64 + tid] = o;
  }
}

__global__ __launch_bounds__(256) void pool_out_kernel(const float* __restrict__ pooled,
    const float* __restrict__ pWo, const float* __restrict__ pool_q, float* __restrict__ pooledf)
{
  const int idx = blockIdx.x*256 + threadIdx.x;   // 16*768
  const int r = idx / 768, c = idx % 768;
  float acc = pool_q[c];
  const float* pr = pooled + (size_t)r*768;
  for (int k = 0; k < 768; ++k) acc += pr[k] * pWo[(size_t)k*768 + c];
  pooledf[idx] = acc;
}

__global__ __launch_bounds__(256) void head_kernel(const bf16* __restrict__ hl,
    const float* __restrict__ Wh, float* __restrict__ out)
{
  const int idx = blockIdx.x*256 + threadIdx.x;
  if (idx >= 16*NCLS) return;
  const int r = idx / NCLS, c = idx % NCLS;
  const bf16* hr = hl + (size_t)r*768;
  float acc = 0.f;
  for (int k = 0; k < 768; ++k) acc += b2f(hr[k]) * Wh[(size_t)k*NCLS + c];
  out[idx] = acc;
}

// ---------------------------------------------------------------- host
extern "C" void kernel_launch(void* const* d_in, const int* in_sizes, int n_in,
                              void* d_out, int out_size, void* d_ws, size_t ws_size,
                              hipStream_t stream)
{
  const float* patches    = (const float*)d_in[0];
  const int*   ppos       = (const int*)d_in[1];
  const int*   image_ids  = (const int*)d_in[2];
  const int*   lengths    = (const int*)d_in[3];
  const float* emb_ln_g   = (const float*)d_in[4];
  const float* W_emb      = (const float*)d_in[5];
  const float* b_emb      = (const float*)d_in[6];
  const float* emb_ln2_g  = (const float*)d_in[7];
  const float* pos_h      = (const float*)d_in[8];
  const float* pos_w      = (const float*)d_in[9];
  const float* ln_attn_g  = (const float*)d_in[10];
  const float* Wq         = (const float*)d_in[11];
  const float* Wkv        = (const float*)d_in[12];
  const float* qn_g       = (const float*)d_in[13];
  const float* kn_g       = (const float*)d_in[14];
  const float* Wo         = (const float*)d_in[15];
  const float* ln_ff_g    = (const float*)d_in[16];
  const float* W1         = (const float*)d_in[17];
  const float* b1         = (const float*)d_in[18];
  const float* W2         = (const float*)d_in[19];
  const float* b2v        = (const float*)d_in[20];
  const float* final_ln_g = (const float*)d_in[21];
  const float* pool_q     = (const float*)d_in[22];
  const float* pool_ln_g  = (const float*)d_in[23];
  const float* pWq        = (const float*)d_in[24];
  const float* pWkv       = (const float*)d_in[25];
  const float* p_qn_g     = (const float*)d_in[26];
  const float* p_kn_g     = (const float*)d_in[27];
  const float* pWo        = (const float*)d_in[28];
  const float* head_ln_g  = (const float*)d_in[29];
  const float* W_head     = (const float*)d_in[30];

  char* ws = (char*)d_ws;
  size_t off = 0;
  auto alloc = [&](size_t sz){ size_t r = off; off += (sz + 255) & ~(size_t)255; return r; };

  const size_t o_WembT = alloc((size_t)768*768*2);
  size_t o_QKVT[4], o_WoT[4], o_W1T[4], o_W2T[4];
  for (int l = 0; l < NLAYER; ++l) {
    o_QKVT[l] = alloc((size_t)2304*768*2);
    o_WoT[l]  = alloc((size_t)768*768*2);
    o_W1T[l]  = alloc((size_t)3072*768*2);
    o_W2T[l]  = alloc((size_t)768*3072*2);
  }
  const size_t o_pWkvT = alloc((size_t)1536*768*2);
  const size_t o_x     = alloc((size_t)MR*768*4);
  const size_t o_xn    = alloc((size_t)MR*768*2);
  const size_t o_qkv   = alloc((size_t)MR*2304*4);   // also reused for h (bf16) and pool kv
  const size_t o_Qb    = alloc((size_t)MR*768*2);
  const size_t o_Kb    = alloc((size_t)MR*768*2);
  const size_t o_Vb    = alloc((size_t)MR*768*2);
  const size_t o_Ob    = alloc((size_t)MR*768*2);
  const size_t o_qp    = alloc((size_t)768*4);
  const size_t o_pool  = alloc((size_t)16*768*4);
  const size_t o_poolf = alloc((size_t)16*768*4);
  const size_t o_hl    = alloc((size_t)16*768*2);
  if (off > ws_size) return;  // workspace too small: fail visibly (poisoned out)

  float* x    = (float*)(ws + o_x);
  bf16*  xn   = (bf16*)(ws + o_xn);
  float* qkv  = (float*)(ws + o_qkv);
  bf16*  hb   = (bf16*)(ws + o_qkv);   // aliases qkv, used after rmsqkv consumed it
  bf16*  Qb   = (bf16*)(ws + o_Qb);
  bf16*  Kb   = (bf16*)(ws + o_Kb);
  bf16*  Vb   = (bf16*)(ws + o_Vb);
  bf16*  Ob   = (bf16*)(ws + o_Ob);
  float* qp   = (float*)(ws + o_qp);
  float* pooled  = (float*)(ws + o_pool);
  float* pooledf = (float*)(ws + o_poolf);
  bf16*  hl   = (bf16*)(ws + o_hl);

  // ---- batched weight transpose + bf16 convert
  TDesc td; int ne = 0, total = 0;
  auto add = [&](const float* s, size_t dofs, int R, int C){
    td.e[ne].src = s;
    td.e[ne].dst = (bf16*)(ws + dofs);
    td.e[ne].R = R; td.e[ne].C = C;
    td.e[ne].tiles = (R/32)*(C/32); td.e[ne].tC = C/32;
    total += td.e[ne].tiles; ++ne;
  };
  add(W_emb, o_WembT, 768, 768);
  for (int l = 0; l < NLAYER; ++l) {
    add(Wq  + (size_t)l*768*768,  o_QKVT[l],                 768, 768);
    add(Wkv + (size_t)l*768*1536, o_QKVT[l] + (size_t)768*768*2, 768, 1536);
    add(Wo  + (size_t)l*768*768,  o_WoT[l],                  768, 768);
    add(W1  + (size_t)l*768*3072, o_W1T[l],                  768, 3072);
    add(W2  + (size_t)l*3072*768, o_W2T[l],                  3072, 768);
  }
  add(pWkv, o_pWkvT, 768, 1536);
  transpose_kernel<<<total, 256, 0, stream>>>(td, ne);

  // ---- embed
  ln768_kernel<<<MR, 256, 0, stream>>>(patches, emb_ln_g, xn);
  gemm_mfma<1,0,0,0><<<dim3(6,32), 256, 0, stream>>>(xn, (const bf16*)(ws+o_WembT), b_emb,
                                                     qkv, nullptr, MR, 768, 768);
  ln_pos_kernel<<<MR, 256, 0, stream>>>(qkv, emb_ln2_g, pos_h, pos_w, ppos, x);

  // ---- transformer layers
  for (int l = 0; l < NLAYER; ++l) {
    ln768_kernel<<<MR, 256, 0, stream>>>(x, ln_attn_g + (size_t)l*768, xn);
    gemm_mfma<0,0,0,0><<<dim3(18,32), 256, 0, stream>>>(xn, (const bf16*)(ws+o_QKVT[l]), nullptr,
                                                        qkv, nullptr, MR, 2304, 768);
    rmsqkv_simple<<<MR*NH/4, 256, 0, stream>>>(qkv, qn_g + (size_t)l*768, kn_g + (size_t)l*768,
                                               Qb, Kb, Vb);
    attn_simple<<<dim3(NTOK/4, NH, NB), 256, 0, stream>>>(Qb, Kb, Vb, Ob, image_ids, lengths);
    gemm_mfma<0,1,0,0><<<dim3(6,32), 256, 0, stream>>>(Ob, (const bf16*)(ws+o_WoT[l]), nullptr,
                                                       x, nullptr, MR, 768, 768);
    ln768_kernel<<<MR, 256, 0, stream>>>(x, ln_ff_g + (size_t)l*768, xn);
    gemm_mfma<1,0,1,1><<<dim3(24,32), 256, 0, stream>>>(xn, (const bf16*)(ws+o_W1T[l]), b1 + (size_t)l*3072,
                                                        nullptr, hb, MR, 3072, 768);
    gemm_mfma<1,1,0,0><<<dim3(6,32), 256, 0, stream>>>(hb, (const bf16*)(ws+o_W2T[l]), b2v + (size_t)l*768,
                                                       x, nullptr, MR, 768, 3072);
  }

  // ---- final LN + pooling + head
  ln768_kernel<<<MR, 256, 0, stream>>>(x, final_ln_g, xn);
  gemm_mfma<0,0,0,0><<<dim3(12,32), 256, 0, stream>>>(xn, (const bf16*)(ws+o_pWkvT), nullptr,
                                                      qkv, nullptr, MR, 1536, 768);
  pool_q_kernel<<<NH, 256, 0, stream>>>(pool_q, pool_ln_g, pWq, p_qn_g, qp);
  pool_attn_kernel<<<dim3(NH,NIMG,NB), 256, 0, stream>>>(qkv, qp, p_kn_g, image_ids, lengths, pooled);
  pool_out_kernel<<<48, 256, 0, stream>>>(pooled, pWo, pool_q, pooledf);
  ln768_kernel<<<16, 256, 0, stream>>>(pooledf, head_ln_g, hl);
  head_kernel<<<(16*NCLS + 255)/256, 256, 0, stream>>>(hl, W_head, (float*)d_out);
}

// Round 4
// 1404.247 us; speedup vs baseline: 3.5011x; 3.5011x over previous
//
#include <hip/hip_runtime.h>
#include <hip/hip_bf16.h>
#include <math.h>

using bf16 = __hip_bfloat16;
typedef short s16x8 __attribute__((ext_vector_type(8)));
typedef float f32x4 __attribute__((ext_vector_type(4)));

#define DEVI __device__ __forceinline__

static constexpr int NB    = 4;
static constexpr int NTOK  = 1024;
static constexpr int DIM   = 768;
static constexpr int NH    = 12;
static constexpr int MLPD  = 3072;
static constexpr int NLAYER= 4;
static constexpr int NIMG  = 4;
static constexpr int NCLS  = 1000;
static constexpr int MR    = NB * NTOK;   // 4096 rows

DEVI float b2f(bf16 v){ return __bfloat162float(v); }
DEVI bf16  f2b(float v){ return __float2bfloat16(v); }

DEVI void async16(const void* g, void* l) {
  __builtin_amdgcn_global_load_lds((const __attribute__((address_space(1))) void*)g,
                                   (__attribute__((address_space(3))) void*)l, 16, 0, 0);
}

DEVI f32x4 mfma16(s16x8 a, s16x8 b, f32x4 c) {
  return __builtin_amdgcn_mfma_f32_16x16x32_bf16(a, b, c, 0, 0, 0);
}

DEVI float block_sum(float v, float* scratch, int tid) {
  #pragma unroll
  for (int o = 32; o >= 1; o >>= 1) v += __shfl_xor(v, o);
  __syncthreads();
  if ((tid & 63) == 0) scratch[tid >> 6] = v;
  __syncthreads();
  return scratch[0] + scratch[1] + scratch[2] + scratch[3];
}

DEVI float block_max(float v, float* scratch, int tid) {
  #pragma unroll
  for (int o = 32; o >= 1; o >>= 1) v = fmaxf(v, __shfl_xor(v, o));
  __syncthreads();
  if ((tid & 63) == 0) scratch[tid >> 6] = v;
  __syncthreads();
  return fmaxf(fmaxf(scratch[0], scratch[1]), fmaxf(scratch[2], scratch[3]));
}

// ---------------------------------------------------------------- transpose + f32->bf16 convert
struct bh4 { bf16 a, b, c, d; };
struct TEntry { const float* src; bf16* dst; int R, C, tiles, tC; };
struct TDesc  { TEntry e[22]; };

__global__ __launch_bounds__(256) void transpose_kernel(TDesc D, int nent) {
  int bid = blockIdx.x, ei = 0;
  while (ei < nent - 1 && bid >= D.e[ei].tiles) { bid -= D.e[ei].tiles; ++ei; }
  const TEntry E = D.e[ei];
  const int tr = bid / E.tC, tc = bid % E.tC;
  __shared__ bf16 t[32][33];
  const int tid = threadIdx.x;
  const int lr = tid >> 3, lc = (tid & 7) * 4;
  const float* srow = E.src + (size_t)(tr*32 + lr)*E.C + tc*32 + lc;
  float4 v = *(const float4*)srow;
  t[lr][lc] = f2b(v.x); t[lr][lc+1] = f2b(v.y); t[lr][lc+2] = f2b(v.z); t[lr][lc+3] = f2b(v.w);
  __syncthreads();
  bh4 o;
  o.a = t[lc+0][lr]; o.b = t[lc+1][lr]; o.c = t[lc+2][lr]; o.d = t[lc+3][lr];
  *(bh4*)(E.dst + (size_t)(tc*32 + lr)*E.R + tr*32 + lc) = o;
}

// ---------------------------------------------------------------- LayerNorm (768 cols), f32 in, bf16 out
__global__ __launch_bounds__(256) void ln768_kernel(const float* __restrict__ in,
    const float* __restrict__ g, bf16* __restrict__ out)
{
  __shared__ float scratch[4];
  const int row = blockIdx.x, tid = threadIdx.x;
  const float* p = in + (size_t)row*768;
  const float v0 = p[tid], v1 = p[tid+256], v2 = p[tid+512];
  const float s  = block_sum(v0+v1+v2, scratch, tid);
  const float ss = block_sum(v0*v0+v1*v1+v2*v2, scratch, tid);
  const float mu = s * (1.0f/768.0f);
  const float var = ss * (1.0f/768.0f) - mu*mu;
  const float rstd = rsqrtf(var + 1e-5f);
  bf16* o = out + (size_t)row*768;
  o[tid]     = f2b((v0-mu)*rstd*g[tid]);
  o[tid+256] = f2b((v1-mu)*rstd*g[tid+256]);
  o[tid+512] = f2b((v2-mu)*rstd*g[tid+512]);
}

// LN + positional add (embed stage 2), f32 out
__global__ __launch_bounds__(256) void ln_pos_kernel(const float* __restrict__ in,
    const float* __restrict__ g, const float* __restrict__ pos_h, const float* __restrict__ pos_w,
    const int* __restrict__ ppos, float* __restrict__ out)
{
  __shared__ float scratch[4];
  const int row = blockIdx.x, tid = threadIdx.x;
  const float* p = in + (size_t)row*768;
  const float v0 = p[tid], v1 = p[tid+256], v2 = p[tid+512];
  const float s  = block_sum(v0+v1+v2, scratch, tid);
  const float ss = block_sum(v0*v0+v1*v1+v2*v2, scratch, tid);
  const float mu = s * (1.0f/768.0f);
  const float rstd = rsqrtf(ss*(1.0f/768.0f) - mu*mu + 1e-5f);
  const int p0 = ppos[row*2], p1 = ppos[row*2+1];
  const float* ph = pos_h + (size_t)p0*768;
  const float* pw = pos_w + (size_t)p1*768;
  float* o = out + (size_t)row*768;
  o[tid]     = (v0-mu)*rstd*g[tid]     + ph[tid]     + pw[tid];
  o[tid+256] = (v1-mu)*rstd*g[tid+256] + ph[tid+256] + pw[tid+256];
  o[tid+512] = (v2-mu)*rstd*g[tid+512] + ph[tid+512] + pw[tid+512];
}

// ---------------------------------------------------------------- GEMM (MFMA, m97-style)
// C[M,Nn] = A[M,K](bf16) @ W[K,Nn] given BT = W^T [Nn,K] row-major bf16.
template<int DO_BIAS, int DO_RES, int DO_GELU, int OUT_BF16>
__global__ __launch_bounds__(256)
void gemm_mfma(const bf16* __restrict__ A, const bf16* __restrict__ BT,
               const float* __restrict__ bias, float* __restrict__ Cf,
               bf16* __restrict__ Cb, int M, int Nn, int K)
{
  __shared__ bf16 As[128*32];
  __shared__ bf16 Bs[128*32];
  const int tid = threadIdx.x;
  const int wid = tid >> 6, lane = tid & 63;
  const int quad = lane >> 4, l15 = lane & 15;
  const int wy = wid >> 1, wx = wid & 1;
  const int m0 = blockIdx.y * 128, n0 = blockIdx.x * 128;
  const int ar = lane >> 2;            // row within 16-row staging group
  const int ac = (lane & 3) * 16;      // 16B chunk within 64B row

  f32x4 acc[4][4];
  #pragma unroll
  for (int i = 0; i < 4; ++i)
    #pragma unroll
    for (int j = 0; j < 4; ++j) acc[i][j] = (f32x4){0.f,0.f,0.f,0.f};

  for (int k0 = 0; k0 < K; k0 += 32) {
    #pragma unroll
    for (int c = 0; c < 2; ++c) {
      const int rb = wid*16 + c*64;
      async16((const char*)A  + ((size_t)(m0 + rb + ar)*K + k0)*2 + ac, (char*)As + rb*64);
      async16((const char*)BT + ((size_t)(n0 + rb + ar)*K + k0)*2 + ac, (char*)Bs + rb*64);
    }
    __syncthreads();
    s16x8 af[4], bfr[4];
    #pragma unroll
    for (int mt = 0; mt < 4; ++mt)
      af[mt] = *(const s16x8*)((const char*)As + (wy*64 + mt*16 + l15)*64 + quad*16);
    #pragma unroll
    for (int nt = 0; nt < 4; ++nt)
      bfr[nt] = *(const s16x8*)((const char*)Bs + (wx*64 + nt*16 + l15)*64 + quad*16);
    #pragma unroll
    for (int mt = 0; mt < 4; ++mt)
      #pragma unroll
      for (int nt = 0; nt < 4; ++nt)
        acc[mt][nt] = mfma16(af[mt], bfr[nt], acc[mt][nt]);
    __syncthreads();
  }

  #pragma unroll
  for (int nt = 0; nt < 4; ++nt) {
    const int col = n0 + wx*64 + nt*16 + l15;
    float bv = 0.f;
    if constexpr (DO_BIAS) bv = bias[col];
    #pragma unroll
    for (int mt = 0; mt < 4; ++mt) {
      #pragma unroll
      for (int r = 0; r < 4; ++r) {
        const int row = m0 + wy*64 + mt*16 + quad*4 + r;
        float v = acc[mt][nt][r];
        if constexpr (DO_BIAS) v += bv;
        if constexpr (DO_GELU) v = 0.5f*v*(1.0f + erff(v*0.70710678118654752f));
        const size_t idx = (size_t)row*Nn + col;
        if constexpr (OUT_BF16) Cb[idx] = f2b(v);
        else if constexpr (DO_RES) Cf[idx] += v;
        else Cf[idx] = v;
      }
    }
  }
}

// ---------------------------------------------------------------- qk rmsnorm + split + V-transpose
// qkv: [MR][2304] f32 (q|k|v). Out: Qb/Kb [b][h][n][64] bf16, VTb [b][h][d][1024] bf16.
__global__ __launch_bounds__(256) void rms_qkv_kernel(const float* __restrict__ qkv,
    const float* __restrict__ qg, const float* __restrict__ kg,
    bf16* __restrict__ Qb, bf16* __restrict__ Kb, bf16* __restrict__ VTb)
{
  __shared__ float tile[64*68];
  const int nt = blockIdx.x, h = blockIdx.y, b = blockIdx.z;
  const int tid = threadIdx.x;
  const int bh = b*NH + h;
  const size_t rowbase = (size_t)(b*NTOK + nt*64);
  const int r = tid >> 2, pp = tid & 3;

  auto stage = [&](int off) {
    #pragma unroll
    for (int rr = 0; rr < 4; ++rr) {
      const int idx = rr*256 + tid;
      const int rw = idx >> 4, c4 = (idx & 15) << 2;
      float4 val = *(const float4*)(qkv + (rowbase + rw)*2304 + off + c4);
      *(float4*)(&tile[rw*68 + c4]) = val;
    }
  };

  // ---- Q
  stage(h*64);
  __syncthreads();
  {
    float ssq = 0.f;
    #pragma unroll
    for (int i = 0; i < 16; ++i) { float x = tile[r*68 + pp*16 + i]; ssq += x*x; }
    ssq += __shfl_xor(ssq, 1); ssq += __shfl_xor(ssq, 2);
    const float rn = 8.0f / fmaxf(sqrtf(ssq), 1e-12f);
    bf16* orow = Qb + ((size_t)bh*NTOK + nt*64 + r)*64;
    #pragma unroll
    for (int i = 0; i < 16; ++i) { int d = pp*16+i; orow[d] = f2b(tile[r*68+d]*rn*qg[h*64+d]); }
  }
  __syncthreads();
  // ---- K
  stage(768 + h*64);
  __syncthreads();
  {
    float ssq = 0.f;
    #pragma unroll
    for (int i = 0; i < 16; ++i) { float x = tile[r*68 + pp*16 + i]; ssq += x*x; }
    ssq += __shfl_xor(ssq, 1); ssq += __shfl_xor(ssq, 2);
    const float rn = 8.0f / fmaxf(sqrtf(ssq), 1e-12f);
    bf16* orow = Kb + ((size_t)bh*NTOK + nt*64 + r)*64;
    #pragma unroll
    for (int i = 0; i < 16; ++i) { int d = pp*16+i; orow[d] = f2b(tile[r*68+d]*rn*kg[h*64+d]); }
  }
  __syncthreads();
  // ---- V (transposed out: VT[d][token])
  stage(1536 + h*64);
  __syncthreads();
  {
    const int d = tid >> 2;
    bf16* orow = VTb + ((size_t)bh*64 + d)*NTOK + nt*64;
    #pragma unroll
    for (int i = 0; i < 16; ++i) { int n = pp*16 + i; orow[n] = f2b(tile[n*68 + d]); }
  }
}

// ---------------------------------------------------------------- fused MFMA attention
// grid (16 qtiles, NH, NB); 4 waves, each owns a 16-row q-stripe. No LDS staging of K/V:
// QK^T B-frags are K's natural rows; PV B-frags are VT's natural rows (L1-cached).
// Only P round-trips through per-wave LDS (C-layout -> A-layout). No barriers in k-loop.
__global__ __launch_bounds__(256) void attn_mfma(const bf16* __restrict__ Qb,
    const bf16* __restrict__ Kb, const bf16* __restrict__ VTb, bf16* __restrict__ Ob,
    const int* __restrict__ ids, const int* __restrict__ lens)
{
  __shared__ bf16 Ps[4][16*72];   // per-wave P tile [m=16][j=64], row stride 72 elems (144B)
  __shared__ int  ids_s[NTOK];
  const int qt = blockIdx.x, h = blockIdx.y, b = blockIdx.z;
  const int tid = threadIdx.x;
  const int wid = tid >> 6, lane = tid & 63;
  const int quad = lane >> 4, l15 = lane & 15;
  const int bh = b*NH + h;
  const int q0 = qt*64;
  const int len = lens[b];

  #pragma unroll
  for (int i = 0; i < 4; ++i) ids_s[i*256 + tid] = ids[b*NTOK + i*256 + tid];
  __syncthreads();   // only barrier; waves independent afterwards

  // Q A-frags: A[m=l15][k=quad*8+j]
  const bf16* qrow = Qb + ((size_t)bh*NTOK + q0 + wid*16 + l15)*64;
  const s16x8 aq0 = *(const s16x8*)(qrow + quad*8);
  const s16x8 aq1 = *(const s16x8*)(qrow + 32 + quad*8);

  int idq[4];
  #pragma unroll
  for (int rr = 0; rr < 4; ++rr) idq[rr] = ids_s[q0 + wid*16 + quad*4 + rr];

  // wave-level q-image bitmask
  unsigned qm = 0;
  #pragma unroll
  for (int rr = 0; rr < 4; ++rr) qm |= 1u << (idq[rr] & 31);
  #pragma unroll
  for (int o = 32; o >= 1; o >>= 1) qm |= (unsigned)__shfl_xor((int)qm, o);

  f32x4 oacc[4];
  #pragma unroll
  for (int nt = 0; nt < 4; ++nt) oacc[nt] = (f32x4){0.f,0.f,0.f,0.f};
  float mrow[4] = {-3.0e38f,-3.0e38f,-3.0e38f,-3.0e38f};
  float lrow[4] = {0.f,0.f,0.f,0.f};

  const bf16* Kgb = Kb  + (size_t)bh*NTOK*64;
  const bf16* Vgb = VTb + (size_t)bh*64*NTOK;
  bf16* pw = Ps[wid];

  for (int kt = 0; kt < 16; ++kt) {
    const int k0 = kt*64;
    // per-wave tile skip
    const int idk_l = ids_s[k0 + lane];
    const bool ok = ((k0 + lane) < len) && (((qm >> (idk_l & 31)) & 1u) != 0u);
    if (__ballot(ok) == 0ULL) continue;

    // S = Q K^T : B-frag = K rows (natural layout), direct from global
    f32x4 sA[4];
    #pragma unroll
    for (int jt = 0; jt < 4; ++jt) {
      const bf16* krow = Kgb + (size_t)(k0 + jt*16 + l15)*64;
      const s16x8 bk0 = *(const s16x8*)(krow + quad*8);
      const s16x8 bk1 = *(const s16x8*)(krow + 32 + quad*8);
      f32x4 s = (f32x4){0.f,0.f,0.f,0.f};
      s = mfma16(aq0, bk0, s);
      s = mfma16(aq1, bk1, s);
      sA[jt] = s;
    }
    // mask (C-layout: row m = quad*4+rr, col j = jt*16+l15)
    #pragma unroll
    for (int jt = 0; jt < 4; ++jt) {
      const int j = k0 + jt*16 + l15;
      const int idk = ids_s[j];
      const bool kvld = j < len;
      #pragma unroll
      for (int rr = 0; rr < 4; ++rr)
        sA[jt][rr] = (kvld && idk == idq[rr]) ? sA[jt][rr] : -3.0e38f;
    }
    // online softmax
    float alpha[4], mnew[4];
    #pragma unroll
    for (int rr = 0; rr < 4; ++rr) {
      float mx = fmaxf(fmaxf(sA[0][rr], sA[1][rr]), fmaxf(sA[2][rr], sA[3][rr]));
      mx = fmaxf(mx, __shfl_xor(mx, 1));
      mx = fmaxf(mx, __shfl_xor(mx, 2));
      mx = fmaxf(mx, __shfl_xor(mx, 4));
      mx = fmaxf(mx, __shfl_xor(mx, 8));
      const float mn = fmaxf(mrow[rr], mx);
      mnew[rr] = mn;
      alpha[rr] = expf(mrow[rr] - mn);
      mrow[rr] = mn;
    }
    #pragma unroll
    for (int rr = 0; rr < 4; ++rr) {
      float rs = 0.f;
      #pragma unroll
      for (int jt = 0; jt < 4; ++jt) {
        // guard: fully-masked entries must give 0 even when mnew == -3e38
        const float pv = (sA[jt][rr] > -1.0e38f) ? expf(sA[jt][rr] - mnew[rr]) : 0.0f;
        sA[jt][rr] = pv;
        rs += pv;
      }
      rs += __shfl_xor(rs, 1);
      rs += __shfl_xor(rs, 2);
      rs += __shfl_xor(rs, 4);
      rs += __shfl_xor(rs, 8);
      lrow[rr] = lrow[rr]*alpha[rr] + rs;
      #pragma unroll
      for (int nt = 0; nt < 4; ++nt) oacc[nt][rr] *= alpha[rr];
    }
    // P (C-layout) -> LDS [m][j]
    #pragma unroll
    for (int jt = 0; jt < 4; ++jt)
      #pragma unroll
      for (int rr = 0; rr < 4; ++rr)
        pw[(quad*4+rr)*72 + jt*16 + l15] = f2b(sA[jt][rr]);
    // O += P @ Vtile : A-frag = P[m=l15][j=ss*32+quad*8+..]; B-frag = VT rows direct from global
    #pragma unroll
    for (int ss = 0; ss < 2; ++ss) {
      const s16x8 ap = *(const s16x8*)(pw + l15*72 + ss*32 + quad*8);
      #pragma unroll
      for (int nt = 0; nt < 4; ++nt) {
        const s16x8 bv = *(const s16x8*)(Vgb + (size_t)(nt*16 + l15)*NTOK + k0 + ss*32 + quad*8);
        oacc[nt] = mfma16(ap, bv, oacc[nt]);
      }
    }
  }

  #pragma unroll
  for (int rr = 0; rr < 4; ++rr) {
    const float inv = lrow[rr] > 0.f ? 1.0f/lrow[rr] : 0.0f;
    const int n = q0 + wid*16 + quad*4 + rr;
    bf16* orow = Ob + ((size_t)b*NTOK + n)*768 + h*64;
    #pragma unroll
    for (int nt = 0; nt < 4; ++nt)
      orow[nt*16 + l15] = f2b(oacc[nt][rr]*inv);
  }
}

// ---------------------------------------------------------------- pooling path
__global__ __launch_bounds__(256) void pool_q_kernel(const float* __restrict__ pool_q,
    const float* __restrict__ pool_ln_g, const float* __restrict__ pWq,
    const float* __restrict__ p_qn_g, float* __restrict__ qp)
{
  __shared__ float xn[768];
  __shared__ float scratch[4];
  __shared__ float qraw[64];
  const int h = blockIdx.x, tid = threadIdx.x;
  float v0 = pool_q[tid], v1 = pool_q[tid+256], v2 = pool_q[tid+512];
  const float s  = block_sum(v0+v1+v2, scratch, tid);
  const float ss = block_sum(v0*v0+v1*v1+v2*v2, scratch, tid);
  const float mu = s*(1.0f/768.0f);
  const float rstd = rsqrtf(ss*(1.0f/768.0f) - mu*mu + 1e-5f);
  xn[tid]     = (v0-mu)*rstd*pool_ln_g[tid];
  xn[tid+256] = (v1-mu)*rstd*pool_ln_g[tid+256];
  xn[tid+512] = (v2-mu)*rstd*pool_ln_g[tid+512];
  __syncthreads();
  const int d = tid >> 2, pp = tid & 3;
  const int col = h*64 + d;
  float acc = 0.f;
  for (int k = pp*192; k < (pp+1)*192; ++k) acc += xn[k]*pWq[(size_t)k*768 + col];
  acc += __shfl_xor(acc, 1); acc += __shfl_xor(acc, 2);
  if (pp == 0) qraw[d] = acc;
  __syncthreads();
  if (tid < 64) {
    const float q = qraw[tid];
    float sq = q*q;
    #pragma unroll
    for (int o = 32; o >= 1; o >>= 1) sq += __shfl_xor(sq, o);
    const float rn = 8.0f / fmaxf(sqrtf(sq), 1e-12f);
    qp[h*64 + tid] = q * rn * p_qn_g[h*64 + tid];
  }
}

__global__ __launch_bounds__(256) void pool_attn_kernel(const float* __restrict__ kvp,
    const float* __restrict__ qp, const float* __restrict__ kg,
    const int* __restrict__ ids, const int* __restrict__ lens, float* __restrict__ pooled)
{
  __shared__ float sp[1024];
  __shared__ float qg_s[64];
  __shared__ float scratch[4];
  __shared__ float outred[4][64];
  const int h = blockIdx.x, img = blockIdx.y, b = blockIdx.z;
  const int tid = threadIdx.x;
  const int len = lens[b];
  if (tid < 64) qg_s[tid] = qp[h*64 + tid] * kg[h*64 + tid];
  __syncthreads();

  float smax = -3.0e38f;
  for (int j = tid; j < 1024; j += 256) {
    float sv = -3.0e38f;
    if (j < len && ids[b*NTOK + j] == img) {
      const float* kr = kvp + (size_t)(b*NTOK + j)*1536 + h*64;
      float ssq = 0.f, dq = 0.f;
      #pragma unroll
      for (int dd = 0; dd < 64; dd += 4) {
        float4 k4 = *(const float4*)(kr + dd);
        ssq += k4.x*k4.x + k4.y*k4.y + k4.z*k4.z + k4.w*k4.w;
        dq  += qg_s[dd]*k4.x + qg_s[dd+1]*k4.y + qg_s[dd+2]*k4.z + qg_s[dd+3]*k4.w;
      }
      const float rn = 8.0f / fmaxf(sqrtf(ssq), 1e-12f);
      sv = dq * rn;
    }
    sp[j] = sv;
    smax = fmaxf(smax, sv);
  }
  const float M = block_max(smax, scratch, tid);
  float lsum = 0.f;
  for (int j = tid; j < 1024; j += 256) {
    const float p = (sp[j] > -1.0e38f) ? expf(sp[j] - M) : 0.0f;
    sp[j] = p;
    lsum += p;
  }
  const float L = block_sum(lsum, scratch, tid);
  const float invL = L > 0.f ? 1.0f / L : 0.0f;

  const int d = tid & 63, jg = tid >> 6;
  float acc = 0.f;
  for (int j = jg; j < 1024; j += 4) {
    const float p = sp[j];
    if (p > 0.f) acc += p * kvp[(size_t)(b*NTOK + j)*1536 + 768 + h*64 + d];
  }
  outred[jg][d] = acc;
  __syncthreads();
  if (tid < 64) {
    const float o = (outred[0][tid] + outred[1][tid] + outred[2][tid] + outred[3][tid]) * invL;
    pooled[((size_t)b*NIMG + img)*768 + h*64 + tid] = o;
  }
}

__global__ __launch_bounds__(256) void pool_out_kernel(const float* __restrict__ pooled,
    const float* __restrict__ pWo, const float* __restrict__ pool_q, float* __restrict__ pooledf)
{
  const int idx = blockIdx.x*256 + threadIdx.x;   // 16*768
  const int r = idx / 768, c = idx % 768;
  float acc = pool_q[c];
  const float* pr = pooled + (size_t)r*768;
  for (int k = 0; k < 768; ++k) acc += pr[k] * pWo[(size_t)k*768 + c];
  pooledf[idx] = acc;
}

__global__ __launch_bounds__(256) void head_kernel(const bf16* __restrict__ hl,
    const float* __restrict__ Wh, float* __restrict__ out)
{
  const int idx = blockIdx.x*256 + threadIdx.x;
  if (idx >= 16*NCLS) return;
  const int r = idx / NCLS, c = idx % NCLS;
  const bf16* hr = hl + (size_t)r*768;
  float acc = 0.f;
  for (int k = 0; k < 768; ++k) acc += b2f(hr[k]) * Wh[(size_t)k*NCLS + c];
  out[idx] = acc;
}

// ---------------------------------------------------------------- host
extern "C" void kernel_launch(void* const* d_in, const int* in_sizes, int n_in,
                              void* d_out, int out_size, void* d_ws, size_t ws_size,
                              hipStream_t stream)
{
  const float* patches    = (const float*)d_in[0];
  const int*   ppos       = (const int*)d_in[1];
  const int*   image_ids  = (const int*)d_in[2];
  const int*   lengths    = (const int*)d_in[3];
  const float* emb_ln_g   = (const float*)d_in[4];
  const float* W_emb      = (const float*)d_in[5];
  const float* b_emb      = (const float*)d_in[6];
  const float* emb_ln2_g  = (const float*)d_in[7];
  const float* pos_h      = (const float*)d_in[8];
  const float* pos_w      = (const float*)d_in[9];
  const float* ln_attn_g  = (const float*)d_in[10];
  const float* Wq         = (const float*)d_in[11];
  const float* Wkv        = (const float*)d_in[12];
  const float* qn_g       = (const float*)d_in[13];
  const float* kn_g       = (const float*)d_in[14];
  const float* Wo         = (const float*)d_in[15];
  const float* ln_ff_g    = (const float*)d_in[16];
  const float* W1         = (const float*)d_in[17];
  const float* b1         = (const float*)d_in[18];
  const float* W2         = (const float*)d_in[19];
  const float* b2v        = (const float*)d_in[20];
  const float* final_ln_g = (const float*)d_in[21];
  const float* pool_q     = (const float*)d_in[22];
  const float* pool_ln_g  = (const float*)d_in[23];
  const float* pWq        = (const float*)d_in[24];
  const float* pWkv       = (const float*)d_in[25];
  const float* p_qn_g     = (const float*)d_in[26];
  const float* p_kn_g     = (const float*)d_in[27];
  const float* pWo        = (const float*)d_in[28];
  const float* head_ln_g  = (const float*)d_in[29];
  const float* W_head     = (const float*)d_in[30];

  char* ws = (char*)d_ws;
  size_t off = 0;
  auto alloc = [&](size_t sz){ size_t r = off; off += (sz + 255) & ~(size_t)255; return r; };

  const size_t o_WembT = alloc((size_t)768*768*2);
  size_t o_QKVT[4], o_WoT[4], o_W1T[4], o_W2T[4];
  for (int l = 0; l < NLAYER; ++l) {
    o_QKVT[l] = alloc((size_t)2304*768*2);
    o_WoT[l]  = alloc((size_t)768*768*2);
    o_W1T[l]  = alloc((size_t)3072*768*2);
    o_W2T[l]  = alloc((size_t)768*3072*2);
  }
  const size_t o_pWkvT = alloc((size_t)1536*768*2);
  const size_t o_x     = alloc((size_t)MR*768*4);
  const size_t o_xn    = alloc((size_t)MR*768*2);
  const size_t o_qkv   = alloc((size_t)MR*2304*4);   // also reused for h (bf16) and pool kv
  const size_t o_Qb    = alloc((size_t)MR*768*2);
  const size_t o_Kb    = alloc((size_t)MR*768*2);
  const size_t o_VT    = alloc((size_t)MR*768*2);
  const size_t o_Ob    = alloc((size_t)MR*768*2);
  const size_t o_qp    = alloc((size_t)768*4);
  const size_t o_pool  = alloc((size_t)16*768*4);
  const size_t o_poolf = alloc((size_t)16*768*4);
  const size_t o_hl    = alloc((size_t)16*768*2);
  if (off > ws_size) return;  // workspace too small: fail visibly (poisoned out)

  float* x    = (float*)(ws + o_x);
  bf16*  xn   = (bf16*)(ws + o_xn);
  float* qkv  = (float*)(ws + o_qkv);
  bf16*  hb   = (bf16*)(ws + o_qkv);   // aliases qkv, used after rms_qkv consumed it
  bf16*  Qb   = (bf16*)(ws + o_Qb);
  bf16*  Kb   = (bf16*)(ws + o_Kb);
  bf16*  VTb  = (bf16*)(ws + o_VT);
  bf16*  Ob   = (bf16*)(ws + o_Ob);
  float* qp   = (float*)(ws + o_qp);
  float* pooled  = (float*)(ws + o_pool);
  float* pooledf = (float*)(ws + o_poolf);
  bf16*  hl   = (bf16*)(ws + o_hl);

  // ---- batched weight transpose + bf16 convert
  TDesc td; int ne = 0, total = 0;
  auto add = [&](const float* s, size_t dofs, int R, int C){
    td.e[ne].src = s;
    td.e[ne].dst = (bf16*)(ws + dofs);
    td.e[ne].R = R; td.e[ne].C = C;
    td.e[ne].tiles = (R/32)*(C/32); td.e[ne].tC = C/32;
    total += td.e[ne].tiles; ++ne;
  };
  add(W_emb, o_WembT, 768, 768);
  for (int l = 0; l < NLAYER; ++l) {
    add(Wq  + (size_t)l*768*768,  o_QKVT[l],                 768, 768);
    add(Wkv + (size_t)l*768*1536, o_QKVT[l] + (size_t)768*768*2, 768, 1536);
    add(Wo  + (size_t)l*768*768,  o_WoT[l],                  768, 768);
    add(W1  + (size_t)l*768*3072, o_W1T[l],                  768, 3072);
    add(W2  + (size_t)l*3072*768, o_W2T[l],                  3072, 768);
  }
  add(pWkv, o_pWkvT, 768, 1536);
  transpose_kernel<<<total, 256, 0, stream>>>(td, ne);

  // ---- embed
  ln768_kernel<<<MR, 256, 0, stream>>>(patches, emb_ln_g, xn);
  gemm_mfma<1,0,0,0><<<dim3(6,32), 256, 0, stream>>>(xn, (const bf16*)(ws+o_WembT), b_emb,
                                                     qkv, nullptr, MR, 768, 768);
  ln_pos_kernel<<<MR, 256, 0, stream>>>(qkv, emb_ln2_g, pos_h, pos_w, ppos, x);

  // ---- transformer layers
  for (int l = 0; l < NLAYER; ++l) {
    ln768_kernel<<<MR, 256, 0, stream>>>(x, ln_attn_g + (size_t)l*768, xn);
    gemm_mfma<0,0,0,0><<<dim3(18,32), 256, 0, stream>>>(xn, (const bf16*)(ws+o_QKVT[l]), nullptr,
                                                        qkv, nullptr, MR, 2304, 768);
    rms_qkv_kernel<<<dim3(16,NH,NB), 256, 0, stream>>>(qkv, qn_g + (size_t)l*768, kn_g + (size_t)l*768,
                                                       Qb, Kb, VTb);
    attn_mfma<<<dim3(16,NH,NB), 256, 0, stream>>>(Qb, Kb, VTb, Ob, image_ids, lengths);
    gemm_mfma<0,1,0,0><<<dim3(6,32), 256, 0, stream>>>(Ob, (const bf16*)(ws+o_WoT[l]), nullptr,
                                                       x, nullptr, MR, 768, 768);
    ln768_kernel<<<MR, 256, 0, stream>>>(x, ln_ff_g + (size_t)l*768, xn);
    gemm_mfma<1,0,1,1><<<dim3(24,32), 256, 0, stream>>>(xn, (const bf16*)(ws+o_W1T[l]), b1 + (size_t)l*3072,
                                                        nullptr, hb, MR, 3072, 768);
    gemm_mfma<1,1,0,0><<<dim3(6,32), 256, 0, stream>>>(hb, (const bf16*)(ws+o_W2T[l]), b2v + (size_t)l*768,
                                                       x, nullptr, MR, 768, 3072);
  }

  // ---- final LN + pooling + head
  ln768_kernel<<<MR, 256, 0, stream>>>(x, final_ln_g, xn);
  gemm_mfma<0,0,0,0><<<dim3(12,32), 256, 0, stream>>>(xn, (const bf16*)(ws+o_pWkvT), nullptr,
                                                      qkv, nullptr, MR, 1536, 768);
  pool_q_kernel<<<NH, 256, 0, stream>>>(pool_q, pool_ln_g, pWq, p_qn_g, qp);
  pool_attn_kernel<<<dim3(NH,NIMG,NB), 256, 0, stream>>>(qkv, qp, p_kn_g, image_ids, lengths, pooled);
  pool_out_kernel<<<48, 256, 0, stream>>>(pooled, pWo, pool_q, pooledf);
  ln768_kernel<<<16, 256, 0, stream>>>(pooledf, head_ln_g, hl);
  head_kernel<<<(16*NCLS + 255)/256, 256, 0, stream>>>(hl, W_head, (float*)d_out);
}

// Round 5
// 1350.805 us; speedup vs baseline: 3.6396x; 1.0396x over previous
//
#include <hip/hip_runtime.h>
#include <hip/hip_bf16.h>
#include <math.h>

using bf16 = __hip_bfloat16;
typedef short s16x8 __attribute__((ext_vector_type(8)));
typedef float f32x4 __attribute__((ext_vector_type(4)));

#define DEVI __device__ __forceinline__

static constexpr int NB    = 4;
static constexpr int NTOK  = 1024;
static constexpr int DIM   = 768;
static constexpr int NH    = 12;
static constexpr int MLPD  = 3072;
static constexpr int NLAYER= 4;
static constexpr int NIMG  = 4;
static constexpr int NCLS  = 1000;
static constexpr int MR    = NB * NTOK;   // 4096 rows

DEVI float b2f(bf16 v){ return __bfloat162float(v); }
DEVI bf16  f2b(float v){ return __float2bfloat16(v); }

DEVI void async16(const void* g, void* l) {
  __builtin_amdgcn_global_load_lds((const __attribute__((address_space(1))) void*)g,
                                   (__attribute__((address_space(3))) void*)l, 16, 0, 0);
}

DEVI f32x4 mfma16(s16x8 a, s16x8 b, f32x4 c) {
  return __builtin_amdgcn_mfma_f32_16x16x32_bf16(a, b, c, 0, 0, 0);
}

DEVI float block_sum(float v, float* scratch, int tid) {
  #pragma unroll
  for (int o = 32; o >= 1; o >>= 1) v += __shfl_xor(v, o);
  __syncthreads();
  if ((tid & 63) == 0) scratch[tid >> 6] = v;
  __syncthreads();
  return scratch[0] + scratch[1] + scratch[2] + scratch[3];
}

DEVI float block_max(float v, float* scratch, int tid) {
  #pragma unroll
  for (int o = 32; o >= 1; o >>= 1) v = fmaxf(v, __shfl_xor(v, o));
  __syncthreads();
  if ((tid & 63) == 0) scratch[tid >> 6] = v;
  __syncthreads();
  return fmaxf(fmaxf(scratch[0], scratch[1]), fmaxf(scratch[2], scratch[3]));
}

// ---------------------------------------------------------------- zero fill
__global__ __launch_bounds__(256) void zero_kernel(float* __restrict__ p, int n) {
  const int i = blockIdx.x*256 + threadIdx.x;
  if (i < n) p[i] = 0.f;
}

// ---------------------------------------------------------------- transpose + f32->bf16 convert
struct bh4 { bf16 a, b, c, d; };
struct TEntry { const float* src; bf16* dst; int R, C, tiles, tC; };
struct TDesc  { TEntry e[22]; };

__global__ __launch_bounds__(256) void transpose_kernel(TDesc D, int nent) {
  int bid = blockIdx.x, ei = 0;
  while (ei < nent - 1 && bid >= D.e[ei].tiles) { bid -= D.e[ei].tiles; ++ei; }
  const TEntry E = D.e[ei];
  const int tr = bid / E.tC, tc = bid % E.tC;
  __shared__ bf16 t[32][33];
  const int tid = threadIdx.x;
  const int lr = tid >> 3, lc = (tid & 7) * 4;
  const float* srow = E.src + (size_t)(tr*32 + lr)*E.C + tc*32 + lc;
  float4 v = *(const float4*)srow;
  t[lr][lc] = f2b(v.x); t[lr][lc+1] = f2b(v.y); t[lr][lc+2] = f2b(v.z); t[lr][lc+3] = f2b(v.w);
  __syncthreads();
  bh4 o;
  o.a = t[lc+0][lr]; o.b = t[lc+1][lr]; o.c = t[lc+2][lr]; o.d = t[lc+3][lr];
  *(bh4*)(E.dst + (size_t)(tc*32 + lr)*E.R + tr*32 + lc) = o;
}

// ---------------------------------------------------------------- LayerNorm (768 cols), f32 in, bf16 out
__global__ __launch_bounds__(256) void ln768_kernel(const float* __restrict__ in,
    const float* __restrict__ g, bf16* __restrict__ out)
{
  __shared__ float scratch[4];
  const int row = blockIdx.x, tid = threadIdx.x;
  const float* p = in + (size_t)row*768;
  const float v0 = p[tid], v1 = p[tid+256], v2 = p[tid+512];
  const float s  = block_sum(v0+v1+v2, scratch, tid);
  const float ss = block_sum(v0*v0+v1*v1+v2*v2, scratch, tid);
  const float mu = s * (1.0f/768.0f);
  const float var = ss * (1.0f/768.0f) - mu*mu;
  const float rstd = rsqrtf(var + 1e-5f);
  bf16* o = out + (size_t)row*768;
  o[tid]     = f2b((v0-mu)*rstd*g[tid]);
  o[tid+256] = f2b((v1-mu)*rstd*g[tid+256]);
  o[tid+512] = f2b((v2-mu)*rstd*g[tid+512]);
}

// LN + positional add (embed stage 2), f32 out
__global__ __launch_bounds__(256) void ln_pos_kernel(const float* __restrict__ in,
    const float* __restrict__ g, const float* __restrict__ pos_h, const float* __restrict__ pos_w,
    const int* __restrict__ ppos, float* __restrict__ out)
{
  __shared__ float scratch[4];
  const int row = blockIdx.x, tid = threadIdx.x;
  const float* p = in + (size_t)row*768;
  const float v0 = p[tid], v1 = p[tid+256], v2 = p[tid+512];
  const float s  = block_sum(v0+v1+v2, scratch, tid);
  const float ss = block_sum(v0*v0+v1*v1+v2*v2, scratch, tid);
  const float mu = s * (1.0f/768.0f);
  const float rstd = rsqrtf(ss*(1.0f/768.0f) - mu*mu + 1e-5f);
  const int p0 = ppos[row*2], p1 = ppos[row*2+1];
  const float* ph = pos_h + (size_t)p0*768;
  const float* pw = pos_w + (size_t)p1*768;
  float* o = out + (size_t)row*768;
  o[tid]     = (v0-mu)*rstd*g[tid]     + ph[tid]     + pw[tid];
  o[tid+256] = (v1-mu)*rstd*g[tid+256] + ph[tid+256] + pw[tid+256];
  o[tid+512] = (v2-mu)*rstd*g[tid+512] + ph[tid+512] + pw[tid+512];
}

// ---------------------------------------------------------------- GEMM (MFMA, m97-style + XOR swizzle + split-K)
// C[M,Nn] = A[M,K](bf16) @ W[K,Nn] given BT = W^T [Nn,K] row-major bf16.
// LDS tile: 64 rows x 128B; slot c of row r holds global 16B-chunk (c ^ (r&7)) of
// m-row 2r+((c^(r&7))>>2). 16 frag lanes hit each bank-group exactly 2x (free).
// SPLITK: grid.z chunks of Kc; partials combined via f32 atomicAdd (bias on z==0).
template<int DO_BIAS, int DO_GELU, int OUT_BF16, int SPLITK, int DO_RES>
__global__ __launch_bounds__(256)
void gemm_mfma(const bf16* __restrict__ A, const bf16* __restrict__ BT,
               const float* __restrict__ bias, float* __restrict__ Cf,
               bf16* __restrict__ Cb, int M, int Nn, int K, int Kc)
{
  __shared__ bf16 As[64*64];   // 64 rows x 128B = 8 KB
  __shared__ bf16 Bs[64*64];
  const int tid = threadIdx.x;
  const int wid = tid >> 6, lane = tid & 63;
  const int quad = lane >> 4, l15 = lane & 15;
  const int wy = wid >> 1, wx = wid & 1;
  const int m0 = blockIdx.y * 128, n0 = blockIdx.x * 128;
  const int rl = lane >> 3;            // local LDS row 0..7
  const int cs = lane & 7;             // slot 0..7

  const int z  = SPLITK ? blockIdx.z : 0;
  const int kb = z * Kc;
  const int ke = kb + Kc;

  f32x4 acc[4][4];
  #pragma unroll
  for (int i = 0; i < 4; ++i)
    #pragma unroll
    for (int j = 0; j < 4; ++j) acc[i][j] = (f32x4){0.f,0.f,0.f,0.f};

  for (int k0 = kb; k0 < ke; k0 += 32) {
    #pragma unroll
    for (int c = 0; c < 2; ++c) {
      const int rbase = wid*8 + c*32;          // LDS row base (wave-uniform)
      const int r_abs = rbase + rl;
      const int ceff  = cs ^ (r_abs & 7);
      const int mg    = 2*r_abs + (ceff >> 2); // m row within 128-tile
      const int jb    = (ceff & 3) * 16;       // byte offset in 64B k-slice
      async16((const char*)A  + ((size_t)(m0 + mg)*K + k0)*2 + jb, (char*)As + rbase*128);
      async16((const char*)BT + ((size_t)(n0 + mg)*K + k0)*2 + jb, (char*)Bs + rbase*128);
    }
    __syncthreads();
    s16x8 af[4], bfr[4];
    #pragma unroll
    for (int mt = 0; mt < 4; ++mt) {
      const int m = wy*64 + mt*16 + l15;
      const int r = m >> 1;
      const int cq = (((m & 1) << 2) | quad) ^ (r & 7);
      af[mt] = *(const s16x8*)((const char*)As + r*128 + cq*16);
    }
    #pragma unroll
    for (int nt = 0; nt < 4; ++nt) {
      const int m = wx*64 + nt*16 + l15;
      const int r = m >> 1;
      const int cq = (((m & 1) << 2) | quad) ^ (r & 7);
      bfr[nt] = *(const s16x8*)((const char*)Bs + r*128 + cq*16);
    }
    #pragma unroll
    for (int mt = 0; mt < 4; ++mt)
      #pragma unroll
      for (int nt = 0; nt < 4; ++nt)
        acc[mt][nt] = mfma16(af[mt], bfr[nt], acc[mt][nt]);
    __syncthreads();
  }

  #pragma unroll
  for (int nt = 0; nt < 4; ++nt) {
    const int col = n0 + wx*64 + nt*16 + l15;
    float bv = 0.f;
    if constexpr (DO_BIAS) bv = bias[col];
    #pragma unroll
    for (int mt = 0; mt < 4; ++mt) {
      #pragma unroll
      for (int r = 0; r < 4; ++r) {
        const int row = m0 + wy*64 + mt*16 + quad*4 + r;
        float v = acc[mt][nt][r];
        const size_t idx = (size_t)row*Nn + col;
        if constexpr (SPLITK) {
          if constexpr (DO_BIAS) { if (z == 0) v += bv; }
          atomicAdd(&Cf[idx], v);
        } else {
          if constexpr (DO_BIAS) v += bv;
          if constexpr (DO_GELU) v = 0.5f*v*(1.0f + erff(v*0.70710678118654752f));
          if constexpr (OUT_BF16) Cb[idx] = f2b(v);
          else if constexpr (DO_RES) Cf[idx] += v;
          else Cf[idx] = v;
        }
      }
    }
  }
}

// ---------------------------------------------------------------- qk rmsnorm + split + V-transpose
// qkv: [MR][2304] f32 (q|k|v). Out: Qb/Kb [b][h][n][64] bf16, VTb [b][h][d][1024] bf16.
__global__ __launch_bounds__(256) void rms_qkv_kernel(const float* __restrict__ qkv,
    const float* __restrict__ qg, const float* __restrict__ kg,
    bf16* __restrict__ Qb, bf16* __restrict__ Kb, bf16* __restrict__ VTb)
{
  __shared__ float tile[64*68];
  const int nt = blockIdx.x, h = blockIdx.y, b = blockIdx.z;
  const int tid = threadIdx.x;
  const int bh = b*NH + h;
  const size_t rowbase = (size_t)(b*NTOK + nt*64);
  const int r = tid >> 2, pp = tid & 3;

  auto stage = [&](int off) {
    #pragma unroll
    for (int rr = 0; rr < 4; ++rr) {
      const int idx = rr*256 + tid;
      const int rw = idx >> 4, c4 = (idx & 15) << 2;
      float4 val = *(const float4*)(qkv + (rowbase + rw)*2304 + off + c4);
      *(float4*)(&tile[rw*68 + c4]) = val;
    }
  };

  // ---- Q
  stage(h*64);
  __syncthreads();
  {
    float ssq = 0.f;
    #pragma unroll
    for (int i = 0; i < 16; ++i) { float x = tile[r*68 + pp*16 + i]; ssq += x*x; }
    ssq += __shfl_xor(ssq, 1); ssq += __shfl_xor(ssq, 2);
    const float rn = 8.0f / fmaxf(sqrtf(ssq), 1e-12f);
    bf16* orow = Qb + ((size_t)bh*NTOK + nt*64 + r)*64;
    #pragma unroll
    for (int i = 0; i < 16; ++i) { int d = pp*16+i; orow[d] = f2b(tile[r*68+d]*rn*qg[h*64+d]); }
  }
  __syncthreads();
  // ---- K
  stage(768 + h*64);
  __syncthreads();
  {
    float ssq = 0.f;
    #pragma unroll
    for (int i = 0; i < 16; ++i) { float x = tile[r*68 + pp*16 + i]; ssq += x*x; }
    ssq += __shfl_xor(ssq, 1); ssq += __shfl_xor(ssq, 2);
    const float rn = 8.0f / fmaxf(sqrtf(ssq), 1e-12f);
    bf16* orow = Kb + ((size_t)bh*NTOK + nt*64 + r)*64;
    #pragma unroll
    for (int i = 0; i < 16; ++i) { int d = pp*16+i; orow[d] = f2b(tile[r*68+d]*rn*kg[h*64+d]); }
  }
  __syncthreads();
  // ---- V (transposed out: VT[d][token])
  stage(1536 + h*64);
  __syncthreads();
  {
    const int d = tid >> 2;
    bf16* orow = VTb + ((size_t)bh*64 + d)*NTOK + nt*64;
    #pragma unroll
    for (int i = 0; i < 16; ++i) { int n = pp*16 + i; orow[n] = f2b(tile[n*68 + d]); }
  }
}

// ---------------------------------------------------------------- fused MFMA attention
__global__ __launch_bounds__(256) void attn_mfma(const bf16* __restrict__ Qb,
    const bf16* __restrict__ Kb, const bf16* __restrict__ VTb, bf16* __restrict__ Ob,
    const int* __restrict__ ids, const int* __restrict__ lens)
{
  __shared__ bf16 Ps[4][16*72];   // per-wave P tile [m=16][j=64], row stride 72 elems
  __shared__ int  ids_s[NTOK];
  const int qt = blockIdx.x, h = blockIdx.y, b = blockIdx.z;
  const int tid = threadIdx.x;
  const int wid = tid >> 6, lane = tid & 63;
  const int quad = lane >> 4, l15 = lane & 15;
  const int bh = b*NH + h;
  const int q0 = qt*64;
  const int len = lens[b];

  #pragma unroll
  for (int i = 0; i < 4; ++i) ids_s[i*256 + tid] = ids[b*NTOK + i*256 + tid];
  __syncthreads();

  const bf16* qrow = Qb + ((size_t)bh*NTOK + q0 + wid*16 + l15)*64;
  const s16x8 aq0 = *(const s16x8*)(qrow + quad*8);
  const s16x8 aq1 = *(const s16x8*)(qrow + 32 + quad*8);

  int idq[4];
  #pragma unroll
  for (int rr = 0; rr < 4; ++rr) idq[rr] = ids_s[q0 + wid*16 + quad*4 + rr];

  unsigned qm = 0;
  #pragma unroll
  for (int rr = 0; rr < 4; ++rr) qm |= 1u << (idq[rr] & 31);
  #pragma unroll
  for (int o = 32; o >= 1; o >>= 1) qm |= (unsigned)__shfl_xor((int)qm, o);

  f32x4 oacc[4];
  #pragma unroll
  for (int nt = 0; nt < 4; ++nt) oacc[nt] = (f32x4){0.f,0.f,0.f,0.f};
  float mrow[4] = {-3.0e38f,-3.0e38f,-3.0e38f,-3.0e38f};
  float lrow[4] = {0.f,0.f,0.f,0.f};

  const bf16* Kgb = Kb  + (size_t)bh*NTOK*64;
  const bf16* Vgb = VTb + (size_t)bh*64*NTOK;
  bf16* pw = Ps[wid];

  for (int kt = 0; kt < 16; ++kt) {
    const int k0 = kt*64;
    const int idk_l = ids_s[k0 + lane];
    const bool ok = ((k0 + lane) < len) && (((qm >> (idk_l & 31)) & 1u) != 0u);
    if (__ballot(ok) == 0ULL) continue;

    f32x4 sA[4];
    #pragma unroll
    for (int jt = 0; jt < 4; ++jt) {
      const bf16* krow = Kgb + (size_t)(k0 + jt*16 + l15)*64;
      const s16x8 bk0 = *(const s16x8*)(krow + quad*8);
      const s16x8 bk1 = *(const s16x8*)(krow + 32 + quad*8);
      f32x4 s = (f32x4){0.f,0.f,0.f,0.f};
      s = mfma16(aq0, bk0, s);
      s = mfma16(aq1, bk1, s);
      sA[jt] = s;
    }
    #pragma unroll
    for (int jt = 0; jt < 4; ++jt) {
      const int j = k0 + jt*16 + l15;
      const int idk = ids_s[j];
      const bool kvld = j < len;
      #pragma unroll
      for (int rr = 0; rr < 4; ++rr)
        sA[jt][rr] = (kvld && idk == idq[rr]) ? sA[jt][rr] : -3.0e38f;
    }
    float alpha[4], mnew[4];
    #pragma unroll
    for (int rr = 0; rr < 4; ++rr) {
      float mx = fmaxf(fmaxf(sA[0][rr], sA[1][rr]), fmaxf(sA[2][rr], sA[3][rr]));
      mx = fmaxf(mx, __shfl_xor(mx, 1));
      mx = fmaxf(mx, __shfl_xor(mx, 2));
      mx = fmaxf(mx, __shfl_xor(mx, 4));
      mx = fmaxf(mx, __shfl_xor(mx, 8));
      const float mn = fmaxf(mrow[rr], mx);
      mnew[rr] = mn;
      alpha[rr] = expf(mrow[rr] - mn);
      mrow[rr] = mn;
    }
    #pragma unroll
    for (int rr = 0; rr < 4; ++rr) {
      float rs = 0.f;
      #pragma unroll
      for (int jt = 0; jt < 4; ++jt) {
        const float pv = (sA[jt][rr] > -1.0e38f) ? expf(sA[jt][rr] - mnew[rr]) : 0.0f;
        sA[jt][rr] = pv;
        rs += pv;
      }
      rs += __shfl_xor(rs, 1);
      rs += __shfl_xor(rs, 2);
      rs += __shfl_xor(rs, 4);
      rs += __shfl_xor(rs, 8);
      lrow[rr] = lrow[rr]*alpha[rr] + rs;
      #pragma unroll
      for (int nt = 0; nt < 4; ++nt) oacc[nt][rr] *= alpha[rr];
    }
    #pragma unroll
    for (int jt = 0; jt < 4; ++jt)
      #pragma unroll
      for (int rr = 0; rr < 4; ++rr)
        pw[(quad*4+rr)*72 + jt*16 + l15] = f2b(sA[jt][rr]);
    #pragma unroll
    for (int ss = 0; ss < 2; ++ss) {
      const s16x8 ap = *(const s16x8*)(pw + l15*72 + ss*32 + quad*8);
      #pragma unroll
      for (int nt = 0; nt < 4; ++nt) {
        const s16x8 bv = *(const s16x8*)(Vgb + (size_t)(nt*16 + l15)*NTOK + k0 + ss*32 + quad*8);
        oacc[nt] = mfma16(ap, bv, oacc[nt]);
      }
    }
  }

  #pragma unroll
  for (int rr = 0; rr < 4; ++rr) {
    const float inv = lrow[rr] > 0.f ? 1.0f/lrow[rr] : 0.0f;
    const int n = q0 + wid*16 + quad*4 + rr;
    bf16* orow = Ob + ((size_t)b*NTOK + n)*768 + h*64;
    #pragma unroll
    for (int nt = 0; nt < 4; ++nt)
      orow[nt*16 + l15] = f2b(oacc[nt][rr]*inv);
  }
}

// ---------------------------------------------------------------- pooling path
__global__ __launch_bounds__(256) void pool_q_kernel(const float* __restrict__ pool_q,
    const float* __restrict__ pool_ln_g, const float* __restrict__ pWq,
    const float* __restrict__ p_qn_g, float* __restrict__ qp)
{
  __shared__ float xn[768];
  __shared__ float scratch[4];
  __shared__ float qraw[64];
  const int h = blockIdx.x, tid = threadIdx.x;
  float v0 = pool_q[tid], v1 = pool_q[tid+256], v2 = pool_q[tid+512];
  const float s  = block_sum(v0+v1+v2, scratch, tid);
  const float ss = block_sum(v0*v0+v1*v1+v2*v2, scratch, tid);
  const float mu = s*(1.0f/768.0f);
  const float rstd = rsqrtf(ss*(1.0f/768.0f) - mu*mu + 1e-5f);
  xn[tid]     = (v0-mu)*rstd*pool_ln_g[tid];
  xn[tid+256] = (v1-mu)*rstd*pool_ln_g[tid+256];
  xn[tid+512] = (v2-mu)*rstd*pool_ln_g[tid+512];
  __syncthreads();
  const int d = tid >> 2, pp = tid & 3;
  const int col = h*64 + d;
  float acc = 0.f;
  for (int k = pp*192; k < (pp+1)*192; ++k) acc += xn[k]*pWq[(size_t)k*768 + col];
  acc += __shfl_xor(acc, 1); acc += __shfl_xor(acc, 2);
  if (pp == 0) qraw[d] = acc;
  __syncthreads();
  if (tid < 64) {
    const float q = qraw[tid];
    float sq = q*q;
    #pragma unroll
    for (int o = 32; o >= 1; o >>= 1) sq += __shfl_xor(sq, o);
    const float rn = 8.0f / fmaxf(sqrtf(sq), 1e-12f);
    qp[h*64 + tid] = q * rn * p_qn_g[h*64 + tid];
  }
}

__global__ __launch_bounds__(256) void pool_attn_kernel(const float* __restrict__ kvp,
    const float* __restrict__ qp, const float* __restrict__ kg,
    const int* __restrict__ ids, const int* __restrict__ lens, float* __restrict__ pooled)
{
  __shared__ float sp[1024];
  __shared__ float qg_s[64];
  __shared__ float scratch[4];
  __shared__ float outred[4][64];
  const int h = blockIdx.x, img = blockIdx.y, b = blockIdx.z;
  const int tid = threadIdx.x;
  const int len = lens[b];
  if (tid < 64) qg_s[tid] = qp[h*64 + tid] * kg[h*64 + tid];
  __syncthreads();

  float smax = -3.0e38f;
  for (int j = tid; j < 1024; j += 256) {
    float sv = -3.0e38f;
    if (j < len && ids[b*NTOK + j] == img) {
      const float* kr = kvp + (size_t)(b*NTOK + j)*1536 + h*64;
      float ssq = 0.f, dq = 0.f;
      #pragma unroll
      for (int dd = 0; dd < 64; dd += 4) {
        float4 k4 = *(const float4*)(kr + dd);
        ssq += k4.x*k4.x + k4.y*k4.y + k4.z*k4.z + k4.w*k4.w;
        dq  += qg_s[dd]*k4.x + qg_s[dd+1]*k4.y + qg_s[dd+2]*k4.z + qg_s[dd+3]*k4.w;
      }
      const float rn = 8.0f / fmaxf(sqrtf(ssq), 1e-12f);
      sv = dq * rn;
    }
    sp[j] = sv;
    smax = fmaxf(smax, sv);
  }
  const float M = block_max(smax, scratch, tid);
  float lsum = 0.f;
  for (int j = tid; j < 1024; j += 256) {
    const float p = (sp[j] > -1.0e38f) ? expf(sp[j] - M) : 0.0f;
    sp[j] = p;
    lsum += p;
  }
  const float L = block_sum(lsum, scratch, tid);
  const float invL = L > 0.f ? 1.0f / L : 0.0f;

  const int d = tid & 63, jg = tid >> 6;
  float acc = 0.f;
  for (int j = jg; j < 1024; j += 4) {
    const float p = sp[j];
    if (p > 0.f) acc += p * kvp[(size_t)(b*NTOK + j)*1536 + 768 + h*64 + d];
  }
  outred[jg][d] = acc;
  __syncthreads();
  if (tid < 64) {
    const float o = (outred[0][tid] + outred[1][tid] + outred[2][tid] + outred[3][tid]) * invL;
    pooled[((size_t)b*NIMG + img)*768 + h*64 + tid] = o;
  }
}

__global__ __launch_bounds__(256) void pool_out_kernel(const float* __restrict__ pooled,
    const float* __restrict__ pWo, const float* __restrict__ pool_q, float* __restrict__ pooledf)
{
  const int idx = blockIdx.x*256 + threadIdx.x;   // 16*768
  const int r = idx / 768, c = idx % 768;
  float acc = pool_q[c];
  const float* pr = pooled + (size_t)r*768;
  for (int k = 0; k < 768; ++k) acc += pr[k] * pWo[(size_t)k*768 + c];
  pooledf[idx] = acc;
}

__global__ __launch_bounds__(256) void head_kernel(const bf16* __restrict__ hl,
    const float* __restrict__ Wh, float* __restrict__ out)
{
  const int idx = blockIdx.x*256 + threadIdx.x;
  if (idx >= 16*NCLS) return;
  const int r = idx / NCLS, c = idx % NCLS;
  const bf16* hr = hl + (size_t)r*768;
  float acc = 0.f;
  for (int k = 0; k < 768; ++k) acc += b2f(hr[k]) * Wh[(size_t)k*NCLS + c];
  out[idx] = acc;
}

// ---------------------------------------------------------------- host
extern "C" void kernel_launch(void* const* d_in, const int* in_sizes, int n_in,
                              void* d_out, int out_size, void* d_ws, size_t ws_size,
                              hipStream_t stream)
{
  const float* patches    = (const float*)d_in[0];
  const int*   ppos       = (const int*)d_in[1];
  const int*   image_ids  = (const int*)d_in[2];
  const int*   lengths    = (const int*)d_in[3];
  const float* emb_ln_g   = (const float*)d_in[4];
  const float* W_emb      = (const float*)d_in[5];
  const float* b_emb      = (const float*)d_in[6];
  const float* emb_ln2_g  = (const float*)d_in[7];
  const float* pos_h      = (const float*)d_in[8];
  const float* pos_w      = (const float*)d_in[9];
  const float* ln_attn_g  = (const float*)d_in[10];
  const float* Wq         = (const float*)d_in[11];
  const float* Wkv        = (const float*)d_in[12];
  const float* qn_g       = (const float*)d_in[13];
  const float* kn_g       = (const float*)d_in[14];
  const float* Wo         = (const float*)d_in[15];
  const float* ln_ff_g    = (const float*)d_in[16];
  const float* W1         = (const float*)d_in[17];
  const float* b1         = (const float*)d_in[18];
  const float* W2         = (const float*)d_in[19];
  const float* b2v        = (const float*)d_in[20];
  const float* final_ln_g = (const float*)d_in[21];
  const float* pool_q     = (const float*)d_in[22];
  const float* pool_ln_g  = (const float*)d_in[23];
  const float* pWq        = (const float*)d_in[24];
  const float* pWkv       = (const float*)d_in[25];
  const float* p_qn_g     = (const float*)d_in[26];
  const float* p_kn_g     = (const float*)d_in[27];
  const float* pWo        = (const float*)d_in[28];
  const float* head_ln_g  = (const float*)d_in[29];
  const float* W_head     = (const float*)d_in[30];

  char* ws = (char*)d_ws;
  size_t off = 0;
  auto alloc = [&](size_t sz){ size_t r = off; off += (sz + 255) & ~(size_t)255; return r; };

  const size_t o_WembT = alloc((size_t)768*768*2);
  size_t o_QKVT[4], o_WoT[4], o_W1T[4], o_W2T[4];
  for (int l = 0; l < NLAYER; ++l) {
    o_QKVT[l] = alloc((size_t)2304*768*2);
    o_WoT[l]  = alloc((size_t)768*768*2);
    o_W1T[l]  = alloc((size_t)3072*768*2);
    o_W2T[l]  = alloc((size_t)768*3072*2);
  }
  const size_t o_pWkvT = alloc((size_t)1536*768*2);
  const size_t o_x     = alloc((size_t)MR*768*4);
  const size_t o_xn    = alloc((size_t)MR*768*2);
  const size_t o_qkv   = alloc((size_t)MR*2304*4);   // also reused for h (bf16) and pool kv
  const size_t o_Qb    = alloc((size_t)MR*768*2);
  const size_t o_Kb    = alloc((size_t)MR*768*2);
  const size_t o_VT    = alloc((size_t)MR*768*2);
  const size_t o_Ob    = alloc((size_t)MR*768*2);
  const size_t o_qp    = alloc((size_t)768*4);
  const size_t o_pool  = alloc((size_t)16*768*4);
  const size_t o_poolf = alloc((size_t)16*768*4);
  const size_t o_hl    = alloc((size_t)16*768*2);
  if (off > ws_size) return;  // workspace too small: fail visibly (poisoned out)

  float* x    = (float*)(ws + o_x);
  bf16*  xn   = (bf16*)(ws + o_xn);
  float* qkv  = (float*)(ws + o_qkv);
  bf16*  hb   = (bf16*)(ws + o_qkv);   // aliases qkv, used after rms_qkv consumed it
  bf16*  Qb   = (bf16*)(ws + o_Qb);
  bf16*  Kb   = (bf16*)(ws + o_Kb);
  bf16*  VTb  = (bf16*)(ws + o_VT);
  bf16*  Ob   = (bf16*)(ws + o_Ob);
  float* qp   = (float*)(ws + o_qp);
  float* pooled  = (float*)(ws + o_pool);
  float* pooledf = (float*)(ws + o_poolf);
  bf16*  hl   = (bf16*)(ws + o_hl);

  // ---- batched weight transpose + bf16 convert
  TDesc td; int ne = 0, total = 0;
  auto add = [&](const float* s, size_t dofs, int R, int C){
    td.e[ne].src = s;
    td.e[ne].dst = (bf16*)(ws + dofs);
    td.e[ne].R = R; td.e[ne].C = C;
    td.e[ne].tiles = (R/32)*(C/32); td.e[ne].tC = C/32;
    total += td.e[ne].tiles; ++ne;
  };
  add(W_emb, o_WembT, 768, 768);
  for (int l = 0; l < NLAYER; ++l) {
    add(Wq  + (size_t)l*768*768,  o_QKVT[l],                 768, 768);
    add(Wkv + (size_t)l*768*1536, o_QKVT[l] + (size_t)768*768*2, 768, 1536);
    add(Wo  + (size_t)l*768*768,  o_WoT[l],                  768, 768);
    add(W1  + (size_t)l*768*3072, o_W1T[l],                  768, 3072);
    add(W2  + (size_t)l*3072*768, o_W2T[l],                  3072, 768);
  }
  add(pWkv, o_pWkvT, 768, 1536);
  transpose_kernel<<<total, 256, 0, stream>>>(td, ne);

  // ---- embed (split-K 2, atomic accumulate into zeroed buffer)
  ln768_kernel<<<MR, 256, 0, stream>>>(patches, emb_ln_g, xn);
  zero_kernel<<<(MR*768 + 255)/256, 256, 0, stream>>>(qkv, MR*768);
  gemm_mfma<1,0,0,1,0><<<dim3(6,32,2), 256, 0, stream>>>(xn, (const bf16*)(ws+o_WembT), b_emb,
                                                         qkv, nullptr, MR, 768, 768, 384);
  ln_pos_kernel<<<MR, 256, 0, stream>>>(qkv, emb_ln2_g, pos_h, pos_w, ppos, x);

  // ---- transformer layers
  for (int l = 0; l < NLAYER; ++l) {
    ln768_kernel<<<MR, 256, 0, stream>>>(x, ln_attn_g + (size_t)l*768, xn);
    gemm_mfma<0,0,0,0,0><<<dim3(18,32), 256, 0, stream>>>(xn, (const bf16*)(ws+o_QKVT[l]), nullptr,
                                                          qkv, nullptr, MR, 2304, 768, 768);
    rms_qkv_kernel<<<dim3(16,NH,NB), 256, 0, stream>>>(qkv, qn_g + (size_t)l*768, kn_g + (size_t)l*768,
                                                       Qb, Kb, VTb);
    attn_mfma<<<dim3(16,NH,NB), 256, 0, stream>>>(Qb, Kb, VTb, Ob, image_ids, lengths);
    // Wo: split-K 2, atomic += into residual x
    gemm_mfma<0,0,0,1,1><<<dim3(6,32,2), 256, 0, stream>>>(Ob, (const bf16*)(ws+o_WoT[l]), nullptr,
                                                           x, nullptr, MR, 768, 768, 384);
    ln768_kernel<<<MR, 256, 0, stream>>>(x, ln_ff_g + (size_t)l*768, xn);
    gemm_mfma<1,1,1,0,0><<<dim3(24,32), 256, 0, stream>>>(xn, (const bf16*)(ws+o_W1T[l]), b1 + (size_t)l*3072,
                                                          nullptr, hb, MR, 3072, 768, 768);
    // W2: split-K 4, atomic += into residual x (bias on z==0)
    gemm_mfma<1,0,0,1,1><<<dim3(6,32,4), 256, 0, stream>>>(hb, (const bf16*)(ws+o_W2T[l]), b2v + (size_t)l*768,
                                                           x, nullptr, MR, 768, 3072, 768);
  }

  // ---- final LN + pooling + head
  ln768_kernel<<<MR, 256, 0, stream>>>(x, final_ln_g, xn);
  gemm_mfma<0,0,0,0,0><<<dim3(12,32), 256, 0, stream>>>(xn, (const bf16*)(ws+o_pWkvT), nullptr,
                                                        qkv, nullptr, MR, 1536, 768, 768);
  pool_q_kernel<<<NH, 256, 0, stream>>>(pool_q, pool_ln_g, pWq, p_qn_g, qp);
  pool_attn_kernel<<<dim3(NH,NIMG,NB), 256, 0, stream>>>(qkv, qp, p_kn_g, image_ids, lengths, pooled);
  pool_out_kernel<<<48, 256, 0, stream>>>(pooled, pWo, pool_q, pooledf);
  ln768_kernel<<<16, 256, 0, stream>>>(pooledf, head_ln_g, hl);
  head_kernel<<<(16*NCLS + 255)/256, 256, 0, stream>>>(hl, W_head, (float*)d_out);
}

// Round 6
// 1288.223 us; speedup vs baseline: 3.8165x; 1.0486x over previous
//
#include <hip/hip_runtime.h>
#include <hip/hip_bf16.h>
#include <math.h>

using bf16 = __hip_bfloat16;
typedef short s16x8 __attribute__((ext_vector_type(8)));
typedef float f32x4 __attribute__((ext_vector_type(4)));

#define DEVI __device__ __forceinline__

static constexpr int NB    = 4;
static constexpr int NTOK  = 1024;
static constexpr int DIM   = 768;
static constexpr int NH    = 12;
static constexpr int MLPD  = 3072;
static constexpr int NLAYER= 4;
static constexpr int NIMG  = 4;
static constexpr int NCLS  = 1000;
static constexpr int MR    = NB * NTOK;   // 4096 rows

DEVI float b2f(bf16 v){ return __bfloat162float(v); }
DEVI bf16  f2b(float v){ return __float2bfloat16(v); }

DEVI void async16(const void* g, void* l) {
  __builtin_amdgcn_global_load_lds((const __attribute__((address_space(1))) void*)g,
                                   (__attribute__((address_space(3))) void*)l, 16, 0, 0);
}

DEVI f32x4 mfma16(s16x8 a, s16x8 b, f32x4 c) {
  return __builtin_amdgcn_mfma_f32_16x16x32_bf16(a, b, c, 0, 0, 0);
}

DEVI float block_sum(float v, float* scratch, int tid) {
  #pragma unroll
  for (int o = 32; o >= 1; o >>= 1) v += __shfl_xor(v, o);
  __syncthreads();
  if ((tid & 63) == 0) scratch[tid >> 6] = v;
  __syncthreads();
  return scratch[0] + scratch[1] + scratch[2] + scratch[3];
}

DEVI float block_max(float v, float* scratch, int tid) {
  #pragma unroll
  for (int o = 32; o >= 1; o >>= 1) v = fmaxf(v, __shfl_xor(v, o));
  __syncthreads();
  if ((tid & 63) == 0) scratch[tid >> 6] = v;
  __syncthreads();
  return fmaxf(fmaxf(scratch[0], scratch[1]), fmaxf(scratch[2], scratch[3]));
}

// ---------------------------------------------------------------- transpose + f32->bf16 convert
struct bh4 { bf16 a, b, c, d; };
struct TEntry { const float* src; bf16* dst; int R, C, tiles, tC; };
struct TDesc  { TEntry e[22]; };

__global__ __launch_bounds__(256) void transpose_kernel(TDesc D, int nent) {
  int bid = blockIdx.x, ei = 0;
  while (ei < nent - 1 && bid >= D.e[ei].tiles) { bid -= D.e[ei].tiles; ++ei; }
  const TEntry E = D.e[ei];
  const int tr = bid / E.tC, tc = bid % E.tC;
  __shared__ bf16 t[32][33];
  const int tid = threadIdx.x;
  const int lr = tid >> 3, lc = (tid & 7) * 4;
  const float* srow = E.src + (size_t)(tr*32 + lr)*E.C + tc*32 + lc;
  float4 v = *(const float4*)srow;
  t[lr][lc] = f2b(v.x); t[lr][lc+1] = f2b(v.y); t[lr][lc+2] = f2b(v.z); t[lr][lc+3] = f2b(v.w);
  __syncthreads();
  bh4 o;
  o.a = t[lc+0][lr]; o.b = t[lc+1][lr]; o.c = t[lc+2][lr]; o.d = t[lc+3][lr];
  *(bh4*)(E.dst + (size_t)(tc*32 + lr)*E.R + tr*32 + lc) = o;
}

// ---------------------------------------------------------------- LayerNorm (768 cols), f32 in, bf16 out
__global__ __launch_bounds__(256) void ln768_kernel(const float* __restrict__ in,
    const float* __restrict__ g, bf16* __restrict__ out)
{
  __shared__ float scratch[4];
  const int row = blockIdx.x, tid = threadIdx.x;
  const float* p = in + (size_t)row*768;
  const float v0 = p[tid], v1 = p[tid+256], v2 = p[tid+512];
  const float s  = block_sum(v0+v1+v2, scratch, tid);
  const float ss = block_sum(v0*v0+v1*v1+v2*v2, scratch, tid);
  const float mu = s * (1.0f/768.0f);
  const float var = ss * (1.0f/768.0f) - mu*mu;
  const float rstd = rsqrtf(var + 1e-5f);
  bf16* o = out + (size_t)row*768;
  o[tid]     = f2b((v0-mu)*rstd*g[tid]);
  o[tid+256] = f2b((v1-mu)*rstd*g[tid+256]);
  o[tid+512] = f2b((v2-mu)*rstd*g[tid+512]);
}

// LN + positional add (embed stage 2), f32 out
__global__ __launch_bounds__(256) void ln_pos_kernel(const float* __restrict__ in,
    const float* __restrict__ g, const float* __restrict__ pos_h, const float* __restrict__ pos_w,
    const int* __restrict__ ppos, float* __restrict__ out)
{
  __shared__ float scratch[4];
  const int row = blockIdx.x, tid = threadIdx.x;
  const float* p = in + (size_t)row*768;
  const float v0 = p[tid], v1 = p[tid+256], v2 = p[tid+512];
  const float s  = block_sum(v0+v1+v2, scratch, tid);
  const float ss = block_sum(v0*v0+v1*v1+v2*v2, scratch, tid);
  const float mu = s * (1.0f/768.0f);
  const float rstd = rsqrtf(ss*(1.0f/768.0f) - mu*mu + 1e-5f);
  const int p0 = ppos[row*2], p1 = ppos[row*2+1];
  const float* ph = pos_h + (size_t)p0*768;
  const float* pw = pos_w + (size_t)p1*768;
  float* o = out + (size_t)row*768;
  o[tid]     = (v0-mu)*rstd*g[tid]     + ph[tid]     + pw[tid];
  o[tid+256] = (v1-mu)*rstd*g[tid+256] + ph[tid+256] + pw[tid+256];
  o[tid+512] = (v2-mu)*rstd*g[tid+512] + ph[tid+512] + pw[tid+512];
}

// ---------------------------------------------------------------- GEMM (MFMA, XOR-swizzled LDS)
// C[M,Nn] = A[M,K](bf16) @ W[K,Nn] given BT = W^T [Nn,K] row-major bf16.
// Tile: 128 (M) x NTILE (N), BK=32. NTILE in {64,128}. LDS rows of 128B hold two
// m-rows' 64B k-slices; slot c of row r holds chunk (c ^ (r&7)) -> conflict-free
// (verified: SQ_LDS_BANK_CONFLICT==0). No split-K: C written exactly once.
template<int DO_BIAS, int DO_GELU, int OUT_BF16, int DO_RES, int NTILE>
__global__ __launch_bounds__(256)
void gemm_mfma(const bf16* __restrict__ A, const bf16* __restrict__ BT,
               const float* __restrict__ bias, float* __restrict__ Cf,
               bf16* __restrict__ Cb, int M, int Nn, int K)
{
  constexpr int NF = NTILE / 32;            // n-frags per wave (2 or 4)
  __shared__ bf16 As[64*64];                // 8 KB
  __shared__ bf16 Bs[(NTILE/2)*64];         // 4 or 8 KB
  const int tid = threadIdx.x;
  const int wid = tid >> 6, lane = tid & 63;
  const int quad = lane >> 4, l15 = lane & 15;
  const int wy = wid >> 1, wx = wid & 1;
  const int m0 = blockIdx.y * 128, n0 = blockIdx.x * NTILE;
  const int rl = lane >> 3;                 // local LDS row 0..7
  const int cs = lane & 7;                  // slot 0..7

  f32x4 acc[4][NF];
  #pragma unroll
  for (int i = 0; i < 4; ++i)
    #pragma unroll
    for (int j = 0; j < NF; ++j) acc[i][j] = (f32x4){0.f,0.f,0.f,0.f};

  for (int k0 = 0; k0 < K; k0 += 32) {
    #pragma unroll
    for (int c = 0; c < 2; ++c) {
      const int rbase = wid*8 + c*32;
      const int r_abs = rbase + rl;
      const int ceff  = cs ^ (r_abs & 7);
      const int mg    = 2*r_abs + (ceff >> 2);
      const int jb    = (ceff & 3) * 16;
      async16((const char*)A + ((size_t)(m0 + mg)*K + k0)*2 + jb, (char*)As + rbase*128);
    }
    #pragma unroll
    for (int c = 0; c < NTILE/64; ++c) {
      const int rbase = wid*8 + c*32;
      const int r_abs = rbase + rl;
      const int ceff  = cs ^ (r_abs & 7);
      const int ng    = 2*r_abs + (ceff >> 2);
      const int jb    = (ceff & 3) * 16;
      async16((const char*)BT + ((size_t)(n0 + ng)*K + k0)*2 + jb, (char*)Bs + rbase*128);
    }
    __syncthreads();
    s16x8 af[4], bfr[NF];
    #pragma unroll
    for (int mt = 0; mt < 4; ++mt) {
      const int m = wy*64 + mt*16 + l15;
      const int r = m >> 1;
      const int cq = (((m & 1) << 2) | quad) ^ (r & 7);
      af[mt] = *(const s16x8*)((const char*)As + r*128 + cq*16);
    }
    #pragma unroll
    for (int nt = 0; nt < NF; ++nt) {
      const int n = wx*(NTILE/2) + nt*16 + l15;
      const int r = n >> 1;
      const int cq = (((n & 1) << 2) | quad) ^ (r & 7);
      bfr[nt] = *(const s16x8*)((const char*)Bs + r*128 + cq*16);
    }
    #pragma unroll
    for (int mt = 0; mt < 4; ++mt)
      #pragma unroll
      for (int nt = 0; nt < NF; ++nt)
        acc[mt][nt] = mfma16(af[mt], bfr[nt], acc[mt][nt]);
    __syncthreads();
  }

  #pragma unroll
  for (int nt = 0; nt < NF; ++nt) {
    const int col = n0 + wx*(NTILE/2) + nt*16 + l15;
    float bv = 0.f;
    if constexpr (DO_BIAS) bv = bias[col];
    #pragma unroll
    for (int mt = 0; mt < 4; ++mt) {
      #pragma unroll
      for (int r = 0; r < 4; ++r) {
        const int row = m0 + wy*64 + mt*16 + quad*4 + r;
        float v = acc[mt][nt][r];
        if constexpr (DO_BIAS) v += bv;
        if constexpr (DO_GELU) v = 0.5f*v*(1.0f + erff(v*0.70710678118654752f));
        const size_t idx = (size_t)row*Nn + col;
        if constexpr (OUT_BF16) Cb[idx] = f2b(v);
        else if constexpr (DO_RES) Cf[idx] += v;
        else Cf[idx] = v;
      }
    }
  }
}

// ---------------------------------------------------------------- qk rmsnorm + split + V-transpose
// qkv: [MR][2304] f32 (q|k|v). Out: Qb/Kb [b][h][n][64] bf16, VTb [b][h][d][1024] bf16.
__global__ __launch_bounds__(256) void rms_qkv_kernel(const float* __restrict__ qkv,
    const float* __restrict__ qg, const float* __restrict__ kg,
    bf16* __restrict__ Qb, bf16* __restrict__ Kb, bf16* __restrict__ VTb)
{
  __shared__ float tile[64*68];
  const int nt = blockIdx.x, h = blockIdx.y, b = blockIdx.z;
  const int tid = threadIdx.x;
  const int bh = b*NH + h;
  const size_t rowbase = (size_t)(b*NTOK + nt*64);
  const int r = tid >> 2, pp = tid & 3;

  auto stage = [&](int off) {
    #pragma unroll
    for (int rr = 0; rr < 4; ++rr) {
      const int idx = rr*256 + tid;
      const int rw = idx >> 4, c4 = (idx & 15) << 2;
      float4 val = *(const float4*)(qkv + (rowbase + rw)*2304 + off + c4);
      *(float4*)(&tile[rw*68 + c4]) = val;
    }
  };

  // ---- Q
  stage(h*64);
  __syncthreads();
  {
    float ssq = 0.f;
    #pragma unroll
    for (int i = 0; i < 16; ++i) { float x = tile[r*68 + pp*16 + i]; ssq += x*x; }
    ssq += __shfl_xor(ssq, 1); ssq += __shfl_xor(ssq, 2);
    const float rn = 8.0f / fmaxf(sqrtf(ssq), 1e-12f);
    bf16* orow = Qb + ((size_t)bh*NTOK + nt*64 + r)*64;
    #pragma unroll
    for (int i = 0; i < 16; ++i) { int d = pp*16+i; orow[d] = f2b(tile[r*68+d]*rn*qg[h*64+d]); }
  }
  __syncthreads();
  // ---- K
  stage(768 + h*64);
  __syncthreads();
  {
    float ssq = 0.f;
    #pragma unroll
    for (int i = 0; i < 16; ++i) { float x = tile[r*68 + pp*16 + i]; ssq += x*x; }
    ssq += __shfl_xor(ssq, 1); ssq += __shfl_xor(ssq, 2);
    const float rn = 8.0f / fmaxf(sqrtf(ssq), 1e-12f);
    bf16* orow = Kb + ((size_t)bh*NTOK + nt*64 + r)*64;
    #pragma unroll
    for (int i = 0; i < 16; ++i) { int d = pp*16+i; orow[d] = f2b(tile[r*68+d]*rn*kg[h*64+d]); }
  }
  __syncthreads();
  // ---- V (transposed out: VT[d][token])
  stage(1536 + h*64);
  __syncthreads();
  {
    const int d = tid >> 2;
    bf16* orow = VTb + ((size_t)bh*64 + d)*NTOK + nt*64;
    #pragma unroll
    for (int i = 0; i < 16; ++i) { int n = pp*16 + i; orow[n] = f2b(tile[n*68 + d]); }
  }
}

// ---------------------------------------------------------------- fused MFMA attention
__global__ __launch_bounds__(256) void attn_mfma(const bf16* __restrict__ Qb,
    const bf16* __restrict__ Kb, const bf16* __restrict__ VTb, bf16* __restrict__ Ob,
    const int* __restrict__ ids, const int* __restrict__ lens)
{
  __shared__ bf16 Ps[4][16*72];   // per-wave P tile [m=16][j=64], row stride 72 elems
  __shared__ int  ids_s[NTOK];
  const int qt = blockIdx.x, h = blockIdx.y, b = blockIdx.z;
  const int tid = threadIdx.x;
  const int wid = tid >> 6, lane = tid & 63;
  const int quad = lane >> 4, l15 = lane & 15;
  const int bh = b*NH + h;
  const int q0 = qt*64;
  const int len = lens[b];

  #pragma unroll
  for (int i = 0; i < 4; ++i) ids_s[i*256 + tid] = ids[b*NTOK + i*256 + tid];
  __syncthreads();

  const bf16* qrow = Qb + ((size_t)bh*NTOK + q0 + wid*16 + l15)*64;
  const s16x8 aq0 = *(const s16x8*)(qrow + quad*8);
  const s16x8 aq1 = *(const s16x8*)(qrow + 32 + quad*8);

  int idq[4];
  #pragma unroll
  for (int rr = 0; rr < 4; ++rr) idq[rr] = ids_s[q0 + wid*16 + quad*4 + rr];

  unsigned qm = 0;
  #pragma unroll
  for (int rr = 0; rr < 4; ++rr) qm |= 1u << (idq[rr] & 31);
  #pragma unroll
  for (int o = 32; o >= 1; o >>= 1) qm |= (unsigned)__shfl_xor((int)qm, o);

  f32x4 oacc[4];
  #pragma unroll
  for (int nt = 0; nt < 4; ++nt) oacc[nt] = (f32x4){0.f,0.f,0.f,0.f};
  float mrow[4] = {-3.0e38f,-3.0e38f,-3.0e38f,-3.0e38f};
  float lrow[4] = {0.f,0.f,0.f,0.f};

  const bf16* Kgb = Kb  + (size_t)bh*NTOK*64;
  const bf16* Vgb = VTb + (size_t)bh*64*NTOK;
  bf16* pw = Ps[wid];

  for (int kt = 0; kt < 16; ++kt) {
    const int k0 = kt*64;
    const int idk_l = ids_s[k0 + lane];
    const bool ok = ((k0 + lane) < len) && (((qm >> (idk_l & 31)) & 1u) != 0u);
    if (__ballot(ok) == 0ULL) continue;

    f32x4 sA[4];
    #pragma unroll
    for (int jt = 0; jt < 4; ++jt) {
      const bf16* krow = Kgb + (size_t)(k0 + jt*16 + l15)*64;
      const s16x8 bk0 = *(const s16x8*)(krow + quad*8);
      const s16x8 bk1 = *(const s16x8*)(krow + 32 + quad*8);
      f32x4 s = (f32x4){0.f,0.f,0.f,0.f};
      s = mfma16(aq0, bk0, s);
      s = mfma16(aq1, bk1, s);
      sA[jt] = s;
    }
    #pragma unroll
    for (int jt = 0; jt < 4; ++jt) {
      const int j = k0 + jt*16 + l15;
      const int idk = ids_s[j];
      const bool kvld = j < len;
      #pragma unroll
      for (int rr = 0; rr < 4; ++rr)
        sA[jt][rr] = (kvld && idk == idq[rr]) ? sA[jt][rr] : -3.0e38f;
    }
    float alpha[4], mnew[4];
    #pragma unroll
    for (int rr = 0; rr < 4; ++rr) {
      float mx = fmaxf(fmaxf(sA[0][rr], sA[1][rr]), fmaxf(sA[2][rr], sA[3][rr]));
      mx = fmaxf(mx, __shfl_xor(mx, 1));
      mx = fmaxf(mx, __shfl_xor(mx, 2));
      mx = fmaxf(mx, __shfl_xor(mx, 4));
      mx = fmaxf(mx, __shfl_xor(mx, 8));
      const float mn = fmaxf(mrow[rr], mx);
      mnew[rr] = mn;
      alpha[rr] = expf(mrow[rr] - mn);
      mrow[rr] = mn;
    }
    #pragma unroll
    for (int rr = 0; rr < 4; ++rr) {
      float rs = 0.f;
      #pragma unroll
      for (int jt = 0; jt < 4; ++jt) {
        const float pv = (sA[jt][rr] > -1.0e38f) ? expf(sA[jt][rr] - mnew[rr]) : 0.0f;
        sA[jt][rr] = pv;
        rs += pv;
      }
      rs += __shfl_xor(rs, 1);
      rs += __shfl_xor(rs, 2);
      rs += __shfl_xor(rs, 4);
      rs += __shfl_xor(rs, 8);
      lrow[rr] = lrow[rr]*alpha[rr] + rs;
      #pragma unroll
      for (int nt = 0; nt < 4; ++nt) oacc[nt][rr] *= alpha[rr];
    }
    #pragma unroll
    for (int jt = 0; jt < 4; ++jt)
      #pragma unroll
      for (int rr = 0; rr < 4; ++rr)
        pw[(quad*4+rr)*72 + jt*16 + l15] = f2b(sA[jt][rr]);
    #pragma unroll
    for (int ss = 0; ss < 2; ++ss) {
      const s16x8 ap = *(const s16x8*)(pw + l15*72 + ss*32 + quad*8);
      #pragma unroll
      for (int nt = 0; nt < 4; ++nt) {
        const s16x8 bv = *(const s16x8*)(Vgb + (size_t)(nt*16 + l15)*NTOK + k0 + ss*32 + quad*8);
        oacc[nt] = mfma16(ap, bv, oacc[nt]);
      }
    }
  }

  #pragma unroll
  for (int rr = 0; rr < 4; ++rr) {
    const float inv = lrow[rr] > 0.f ? 1.0f/lrow[rr] : 0.0f;
    const int n = q0 + wid*16 + quad*4 + rr;
    bf16* orow = Ob + ((size_t)b*NTOK + n)*768 + h*64;
    #pragma unroll
    for (int nt = 0; nt < 4; ++nt)
      orow[nt*16 + l15] = f2b(oacc[nt][rr]*inv);
  }
}

// ---------------------------------------------------------------- pooling path
__global__ __launch_bounds__(256) void pool_q_kernel(const float* __restrict__ pool_q,
    const float* __restrict__ pool_ln_g, const float* __restrict__ pWq,
    const float* __restrict__ p_qn_g, float* __restrict__ qp)
{
  __shared__ float xn[768];
  __shared__ float scratch[4];
  __shared__ float qraw[64];
  const int h = blockIdx.x, tid = threadIdx.x;
  float v0 = pool_q[tid], v1 = pool_q[tid+256], v2 = pool_q[tid+512];
  const float s  = block_sum(v0+v1+v2, scratch, tid);
  const float ss = block_sum(v0*v0+v1*v1+v2*v2, scratch, tid);
  const float mu = s*(1.0f/768.0f);
  const float rstd = rsqrtf(ss*(1.0f/768.0f) - mu*mu + 1e-5f);
  xn[tid]     = (v0-mu)*rstd*pool_ln_g[tid];
  xn[tid+256] = (v1-mu)*rstd*pool_ln_g[tid+256];
  xn[tid+512] = (v2-mu)*rstd*pool_ln_g[tid+512];
  __syncthreads();
  const int d = tid >> 2, pp = tid & 3;
  const int col = h*64 + d;
  float acc = 0.f;
  for (int k = pp*192; k < (pp+1)*192; ++k) acc += xn[k]*pWq[(size_t)k*768 + col];
  acc += __shfl_xor(acc, 1); acc += __shfl_xor(acc, 2);
  if (pp == 0) qraw[d] = acc;
  __syncthreads();
  if (tid < 64) {
    const float q = qraw[tid];
    float sq = q*q;
    #pragma unroll
    for (int o = 32; o >= 1; o >>= 1) sq += __shfl_xor(sq, o);
    const float rn = 8.0f / fmaxf(sqrtf(sq), 1e-12f);
    qp[h*64 + tid] = q * rn * p_qn_g[h*64 + tid];
  }
}

__global__ __launch_bounds__(256) void pool_attn_kernel(const float* __restrict__ kvp,
    const float* __restrict__ qp, const float* __restrict__ kg,
    const int* __restrict__ ids, const int* __restrict__ lens, float* __restrict__ pooled)
{
  __shared__ float sp[1024];
  __shared__ float qg_s[64];
  __shared__ float scratch[4];
  __shared__ float outred[4][64];
  const int h = blockIdx.x, img = blockIdx.y, b = blockIdx.z;
  const int tid = threadIdx.x;
  const int len = lens[b];
  if (tid < 64) qg_s[tid] = qp[h*64 + tid] * kg[h*64 + tid];
  __syncthreads();

  float smax = -3.0e38f;
  for (int j = tid; j < 1024; j += 256) {
    float sv = -3.0e38f;
    if (j < len && ids[b*NTOK + j] == img) {
      const float* kr = kvp + (size_t)(b*NTOK + j)*1536 + h*64;
      float ssq = 0.f, dq = 0.f;
      #pragma unroll
      for (int dd = 0; dd < 64; dd += 4) {
        float4 k4 = *(const float4*)(kr + dd);
        ssq += k4.x*k4.x + k4.y*k4.y + k4.z*k4.z + k4.w*k4.w;
        dq  += qg_s[dd]*k4.x + qg_s[dd+1]*k4.y + qg_s[dd+2]*k4.z + qg_s[dd+3]*k4.w;
      }
      const float rn = 8.0f / fmaxf(sqrtf(ssq), 1e-12f);
      sv = dq * rn;
    }
    sp[j] = sv;
    smax = fmaxf(smax, sv);
  }
  const float M = block_max(smax, scratch, tid);
  float lsum = 0.f;
  for (int j = tid; j < 1024; j += 256) {
    const float p = (sp[j] > -1.0e38f) ? expf(sp[j] - M) : 0.0f;
    sp[j] = p;
    lsum += p;
  }
  const float L = block_sum(lsum, scratch, tid);
  const float invL = L > 0.f ? 1.0f / L : 0.0f;

  const int d = tid & 63, jg = tid >> 6;
  float acc = 0.f;
  for (int j = jg; j < 1024; j += 4) {
    const float p = sp[j];
    if (p > 0.f) acc += p * kvp[(size_t)(b*NTOK + j)*1536 + 768 + h*64 + d];
  }
  outred[jg][d] = acc;
  __syncthreads();
  if (tid < 64) {
    const float o = (outred[0][tid] + outred[1][tid] + outred[2][tid] + outred[3][tid]) * invL;
    pooled[((size_t)b*NIMG + img)*768 + h*64 + tid] = o;
  }
}

__global__ __launch_bounds__(256) void pool_out_kernel(const float* __restrict__ pooled,
    const float* __restrict__ pWo, const float* __restrict__ pool_q, float* __restrict__ pooledf)
{
  const int idx = blockIdx.x*256 + threadIdx.x;   // 16*768
  const int r = idx / 768, c = idx % 768;
  float acc = pool_q[c];
  const float* pr = pooled + (size_t)r*768;
  for (int k = 0; k < 768; ++k) acc += pr[k] * pWo[(size_t)k*768 + c];
  pooledf[idx] = acc;
}

__global__ __launch_bounds__(256) void head_kernel(const bf16* __restrict__ hl,
    const float* __restrict__ Wh, float* __restrict__ out)
{
  const int idx = blockIdx.x*256 + threadIdx.x;
  if (idx >= 16*NCLS) return;
  const int r = idx / NCLS, c = idx % NCLS;
  const bf16* hr = hl + (size_t)r*768;
  float acc = 0.f;
  for (int k = 0; k < 768; ++k) acc += b2f(hr[k]) * Wh[(size_t)k*NCLS + c];
  out[idx] = acc;
}

// ---------------------------------------------------------------- host
extern "C" void kernel_launch(void* const* d_in, const int* in_sizes, int n_in,
                              void* d_out, int out_size, void* d_ws, size_t ws_size,
                              hipStream_t stream)
{
  const float* patches    = (const float*)d_in[0];
  const int*   ppos       = (const int*)d_in[1];
  const int*   image_ids  = (const int*)d_in[2];
  const int*   lengths    = (const int*)d_in[3];
  const float* emb_ln_g   = (const float*)d_in[4];
  const float* W_emb      = (const float*)d_in[5];
  const float* b_emb      = (const float*)d_in[6];
  const float* emb_ln2_g  = (const float*)d_in[7];
  const float* pos_h      = (const float*)d_in[8];
  const float* pos_w      = (const float*)d_in[9];
  const float* ln_attn_g  = (const float*)d_in[10];
  const float* Wq         = (const float*)d_in[11];
  const float* Wkv        = (const float*)d_in[12];
  const float* qn_g       = (const float*)d_in[13];
  const float* kn_g       = (const float*)d_in[14];
  const float* Wo         = (const float*)d_in[15];
  const float* ln_ff_g    = (const float*)d_in[16];
  const float* W1         = (const float*)d_in[17];
  const float* b1         = (const float*)d_in[18];
  const float* W2         = (const float*)d_in[19];
  const float* b2v        = (const float*)d_in[20];
  const float* final_ln_g = (const float*)d_in[21];
  const float* pool_q     = (const float*)d_in[22];
  const float* pool_ln_g  = (const float*)d_in[23];
  const float* pWq        = (const float*)d_in[24];
  const float* pWkv       = (const float*)d_in[25];
  const float* p_qn_g     = (const float*)d_in[26];
  const float* p_kn_g     = (const float*)d_in[27];
  const float* pWo        = (const float*)d_in[28];
  const float* head_ln_g  = (const float*)d_in[29];
  const float* W_head     = (const float*)d_in[30];

  char* ws = (char*)d_ws;
  size_t off = 0;
  auto alloc = [&](size_t sz){ size_t r = off; off += (sz + 255) & ~(size_t)255; return r; };

  const size_t o_WembT = alloc((size_t)768*768*2);
  size_t o_QKVT[4], o_WoT[4], o_W1T[4], o_W2T[4];
  for (int l = 0; l < NLAYER; ++l) {
    o_QKVT[l] = alloc((size_t)2304*768*2);
    o_WoT[l]  = alloc((size_t)768*768*2);
    o_W1T[l]  = alloc((size_t)3072*768*2);
    o_W2T[l]  = alloc((size_t)768*3072*2);
  }
  const size_t o_pWkvT = alloc((size_t)1536*768*2);
  const size_t o_x     = alloc((size_t)MR*768*4);
  const size_t o_xn    = alloc((size_t)MR*768*2);
  const size_t o_qkv   = alloc((size_t)MR*2304*4);   // also reused for h (bf16) and pool kv
  const size_t o_Qb    = alloc((size_t)MR*768*2);
  const size_t o_Kb    = alloc((size_t)MR*768*2);
  const size_t o_VT    = alloc((size_t)MR*768*2);
  const size_t o_Ob    = alloc((size_t)MR*768*2);
  const size_t o_qp    = alloc((size_t)768*4);
  const size_t o_pool  = alloc((size_t)16*768*4);
  const size_t o_poolf = alloc((size_t)16*768*4);
  const size_t o_hl    = alloc((size_t)16*768*2);
  if (off > ws_size) return;  // workspace too small: fail visibly (poisoned out)

  float* x    = (float*)(ws + o_x);
  bf16*  xn   = (bf16*)(ws + o_xn);
  float* qkv  = (float*)(ws + o_qkv);
  bf16*  hb   = (bf16*)(ws + o_qkv);   // aliases qkv, used after rms_qkv consumed it
  bf16*  Qb   = (bf16*)(ws + o_Qb);
  bf16*  Kb   = (bf16*)(ws + o_Kb);
  bf16*  VTb  = (bf16*)(ws + o_VT);
  bf16*  Ob   = (bf16*)(ws + o_Ob);
  float* qp   = (float*)(ws + o_qp);
  float* pooled  = (float*)(ws + o_pool);
  float* pooledf = (float*)(ws + o_poolf);
  bf16*  hl   = (bf16*)(ws + o_hl);

  // ---- batched weight transpose + bf16 convert
  TDesc td; int ne = 0, total = 0;
  auto add = [&](const float* s, size_t dofs, int R, int C){
    td.e[ne].src = s;
    td.e[ne].dst = (bf16*)(ws + dofs);
    td.e[ne].R = R; td.e[ne].C = C;
    td.e[ne].tiles = (R/32)*(C/32); td.e[ne].tC = C/32;
    total += td.e[ne].tiles; ++ne;
  };
  add(W_emb, o_WembT, 768, 768);
  for (int l = 0; l < NLAYER; ++l) {
    add(Wq  + (size_t)l*768*768,  o_QKVT[l],                 768, 768);
    add(Wkv + (size_t)l*768*1536, o_QKVT[l] + (size_t)768*768*2, 768, 1536);
    add(Wo  + (size_t)l*768*768,  o_WoT[l],                  768, 768);
    add(W1  + (size_t)l*768*3072, o_W1T[l],                  768, 3072);
    add(W2  + (size_t)l*3072*768, o_W2T[l],                  3072, 768);
  }
  add(pWkv, o_pWkvT, 768, 1536);
  transpose_kernel<<<total, 256, 0, stream>>>(td, ne);

  // ---- embed
  ln768_kernel<<<MR, 256, 0, stream>>>(patches, emb_ln_g, xn);
  gemm_mfma<1,0,0,0,64><<<dim3(12,32), 256, 0, stream>>>(xn, (const bf16*)(ws+o_WembT), b_emb,
                                                         qkv, nullptr, MR, 768, 768);
  ln_pos_kernel<<<MR, 256, 0, stream>>>(qkv, emb_ln2_g, pos_h, pos_w, ppos, x);

  // ---- transformer layers
  for (int l = 0; l < NLAYER; ++l) {
    ln768_kernel<<<MR, 256, 0, stream>>>(x, ln_attn_g + (size_t)l*768, xn);
    gemm_mfma<0,0,0,0,128><<<dim3(18,32), 256, 0, stream>>>(xn, (const bf16*)(ws+o_QKVT[l]), nullptr,
                                                            qkv, nullptr, MR, 2304, 768);
    rms_qkv_kernel<<<dim3(16,NH,NB), 256, 0, stream>>>(qkv, qn_g + (size_t)l*768, kn_g + (size_t)l*768,
                                                       Qb, Kb, VTb);
    attn_mfma<<<dim3(16,NH,NB), 256, 0, stream>>>(Qb, Kb, VTb, Ob, image_ids, lengths);
    // Wo: residual += into x (single writer per element)
    gemm_mfma<0,0,0,1,64><<<dim3(12,32), 256, 0, stream>>>(Ob, (const bf16*)(ws+o_WoT[l]), nullptr,
                                                           x, nullptr, MR, 768, 768);
    ln768_kernel<<<MR, 256, 0, stream>>>(x, ln_ff_g + (size_t)l*768, xn);
    gemm_mfma<1,1,1,0,128><<<dim3(24,32), 256, 0, stream>>>(xn, (const bf16*)(ws+o_W1T[l]), b1 + (size_t)l*3072,
                                                            nullptr, hb, MR, 3072, 768);
    // W2: residual += into x with bias
    gemm_mfma<1,0,0,1,64><<<dim3(12,32), 256, 0, stream>>>(hb, (const bf16*)(ws+o_W2T[l]), b2v + (size_t)l*768,
                                                           x, nullptr, MR, 768, 3072);
  }

  // ---- final LN + pooling + head
  ln768_kernel<<<MR, 256, 0, stream>>>(x, final_ln_g, xn);
  gemm_mfma<0,0,0,0,128><<<dim3(12,32), 256, 0, stream>>>(xn, (const bf16*)(ws+o_pWkvT), nullptr,
                                                          qkv, nullptr, MR, 1536, 768);
  pool_q_kernel<<<NH, 256, 0, stream>>>(pool_q, pool_ln_g, pWq, p_qn_g, qp);
  pool_attn_kernel<<<dim3(NH,NIMG,NB), 256, 0, stream>>>(qkv, qp, p_kn_g, image_ids, lengths, pooled);
  pool_out_kernel<<<48, 256, 0, stream>>>(pooled, pWo, pool_q, pooledf);
  ln768_kernel<<<16, 256, 0, stream>>>(pooledf, head_ln_g, hl);
  head_kernel<<<(16*NCLS + 255)/256, 256, 0, stream>>>(hl, W_head, (float*)d_out);
}

// Round 7
// 1240.903 us; speedup vs baseline: 3.9620x; 1.0381x over previous
//
#include <hip/hip_runtime.h>
#include <hip/hip_bf16.h>
#include <math.h>

using bf16 = __hip_bfloat16;
typedef short s16x8 __attribute__((ext_vector_type(8)));
typedef float f32x4 __attribute__((ext_vector_type(4)));

#define DEVI __device__ __forceinline__

static constexpr int NB    = 4;
static constexpr int NTOK  = 1024;
static constexpr int DIM   = 768;
static constexpr int NH    = 12;
static constexpr int MLPD  = 3072;
static constexpr int NLAYER= 4;
static constexpr int NIMG  = 4;
static constexpr int NCLS  = 1000;
static constexpr int MR    = NB * NTOK;   // 4096 rows

DEVI float b2f(bf16 v){ return __bfloat162float(v); }
DEVI bf16  f2b(float v){ return __float2bfloat16(v); }

DEVI void async16(const void* g, void* l) {
  __builtin_amdgcn_global_load_lds((const __attribute__((address_space(1))) void*)g,
                                   (__attribute__((address_space(3))) void*)l, 16, 0, 0);
}

DEVI f32x4 mfma16(s16x8 a, s16x8 b, f32x4 c) {
  return __builtin_amdgcn_mfma_f32_16x16x32_bf16(a, b, c, 0, 0, 0);
}

DEVI float block_sum(float v, float* scratch, int tid) {
  #pragma unroll
  for (int o = 32; o >= 1; o >>= 1) v += __shfl_xor(v, o);
  __syncthreads();
  if ((tid & 63) == 0) scratch[tid >> 6] = v;
  __syncthreads();
  return scratch[0] + scratch[1] + scratch[2] + scratch[3];
}

DEVI float block_max(float v, float* scratch, int tid) {
  #pragma unroll
  for (int o = 32; o >= 1; o >>= 1) v = fmaxf(v, __shfl_xor(v, o));
  __syncthreads();
  if ((tid & 63) == 0) scratch[tid >> 6] = v;
  __syncthreads();
  return fmaxf(fmaxf(scratch[0], scratch[1]), fmaxf(scratch[2], scratch[3]));
}

// ---------------------------------------------------------------- transpose + f32->bf16 convert
struct bh4 { bf16 a, b, c, d; };
struct TEntry { const float* src; bf16* dst; int R, C, tiles, tC; };
struct TDesc  { TEntry e[22]; };

__global__ __launch_bounds__(256) void transpose_kernel(TDesc D, int nent) {
  int bid = blockIdx.x, ei = 0;
  while (ei < nent - 1 && bid >= D.e[ei].tiles) { bid -= D.e[ei].tiles; ++ei; }
  const TEntry E = D.e[ei];
  const int tr = bid / E.tC, tc = bid % E.tC;
  __shared__ bf16 t[32][33];
  const int tid = threadIdx.x;
  const int lr = tid >> 3, lc = (tid & 7) * 4;
  const float* srow = E.src + (size_t)(tr*32 + lr)*E.C + tc*32 + lc;
  float4 v = *(const float4*)srow;
  t[lr][lc] = f2b(v.x); t[lr][lc+1] = f2b(v.y); t[lr][lc+2] = f2b(v.z); t[lr][lc+3] = f2b(v.w);
  __syncthreads();
  bh4 o;
  o.a = t[lc+0][lr]; o.b = t[lc+1][lr]; o.c = t[lc+2][lr]; o.d = t[lc+3][lr];
  *(bh4*)(E.dst + (size_t)(tc*32 + lr)*E.R + tr*32 + lc) = o;
}

// ---------------------------------------------------------------- LayerNorm (768 cols), f32 in, bf16 out
__global__ __launch_bounds__(256) void ln768_kernel(const float* __restrict__ in,
    const float* __restrict__ g, bf16* __restrict__ out)
{
  __shared__ float scratch[4];
  const int row = blockIdx.x, tid = threadIdx.x;
  const float* p = in + (size_t)row*768;
  const float v0 = p[tid], v1 = p[tid+256], v2 = p[tid+512];
  const float s  = block_sum(v0+v1+v2, scratch, tid);
  const float ss = block_sum(v0*v0+v1*v1+v2*v2, scratch, tid);
  const float mu = s * (1.0f/768.0f);
  const float var = ss * (1.0f/768.0f) - mu*mu;
  const float rstd = rsqrtf(var + 1e-5f);
  bf16* o = out + (size_t)row*768;
  o[tid]     = f2b((v0-mu)*rstd*g[tid]);
  o[tid+256] = f2b((v1-mu)*rstd*g[tid+256]);
  o[tid+512] = f2b((v2-mu)*rstd*g[tid+512]);
}

// LN + positional add (embed stage 2), f32 out
__global__ __launch_bounds__(256) void ln_pos_kernel(const float* __restrict__ in,
    const float* __restrict__ g, const float* __restrict__ pos_h, const float* __restrict__ pos_w,
    const int* __restrict__ ppos, float* __restrict__ out)
{
  __shared__ float scratch[4];
  const int row = blockIdx.x, tid = threadIdx.x;
  const float* p = in + (size_t)row*768;
  const float v0 = p[tid], v1 = p[tid+256], v2 = p[tid+512];
  const float s  = block_sum(v0+v1+v2, scratch, tid);
  const float ss = block_sum(v0*v0+v1*v1+v2*v2, scratch, tid);
  const float mu = s * (1.0f/768.0f);
  const float rstd = rsqrtf(ss*(1.0f/768.0f) - mu*mu + 1e-5f);
  const int p0 = ppos[row*2], p1 = ppos[row*2+1];
  const float* ph = pos_h + (size_t)p0*768;
  const float* pw = pos_w + (size_t)p1*768;
  float* o = out + (size_t)row*768;
  o[tid]     = (v0-mu)*rstd*g[tid]     + ph[tid]     + pw[tid];
  o[tid+256] = (v1-mu)*rstd*g[tid+256] + ph[tid+256] + pw[tid+256];
  o[tid+512] = (v2-mu)*rstd*g[tid+512] + ph[tid+512] + pw[tid+512];
}

// ---------------------------------------------------------------- GEMM (MFMA, XOR-swizzled LDS, double-buffered)
// C[M,Nn] = A[M,K](bf16) @ W[K,Nn] given BT = W^T [Nn,K] row-major bf16.
// Tile: 128 (M) x NTILE (N), BK=32. Double-buffered staging: next K-tile's
// global_load_lds is in flight across the whole current tile's compute, so the
// vmcnt(0) drain at the single per-iter barrier finds loads already done.
template<int DO_BIAS, int DO_GELU, int OUT_BF16, int DO_RES, int NTILE>
__global__ __launch_bounds__(256)
void gemm_mfma(const bf16* __restrict__ A, const bf16* __restrict__ BT,
               const float* __restrict__ bias, float* __restrict__ Cf,
               bf16* __restrict__ Cb, int M, int Nn, int K)
{
  constexpr int NF = NTILE / 32;            // n-frags per wave (2 or 4)
  __shared__ bf16 As[2][64*64];             // 2 x 8 KB
  __shared__ bf16 Bs[2][(NTILE/2)*64];      // 2 x (4 or 8) KB
  const int tid = threadIdx.x;
  const int wid = tid >> 6, lane = tid & 63;
  const int quad = lane >> 4, l15 = lane & 15;
  const int wy = wid >> 1, wx = wid & 1;
  const int m0 = blockIdx.y * 128, n0 = blockIdx.x * NTILE;
  const int rl = lane >> 3;                 // local LDS row 0..7
  const int cs = lane & 7;                  // slot 0..7

  f32x4 acc[4][NF];
  #pragma unroll
  for (int i = 0; i < 4; ++i)
    #pragma unroll
    for (int j = 0; j < NF; ++j) acc[i][j] = (f32x4){0.f,0.f,0.f,0.f};

  auto stage = [&](int buf, int k0) {
    #pragma unroll
    for (int c = 0; c < 2; ++c) {
      const int rbase = wid*8 + c*32;
      const int r_abs = rbase + rl;
      const int ceff  = cs ^ (r_abs & 7);
      const int mg    = 2*r_abs + (ceff >> 2);
      const int jb    = (ceff & 3) * 16;
      async16((const char*)A + ((size_t)(m0 + mg)*K + k0)*2 + jb, (char*)As[buf] + rbase*128);
    }
    #pragma unroll
    for (int c = 0; c < NTILE/64; ++c) {
      const int rbase = wid*8 + c*32;
      const int r_abs = rbase + rl;
      const int ceff  = cs ^ (r_abs & 7);
      const int ng    = 2*r_abs + (ceff >> 2);
      const int jb    = (ceff & 3) * 16;
      async16((const char*)BT + ((size_t)(n0 + ng)*K + k0)*2 + jb, (char*)Bs[buf] + rbase*128);
    }
  };

  const int nk = K >> 5;
  stage(0, 0);
  for (int kt = 0; kt < nk; ++kt) {
    const int cb = kt & 1;
    __syncthreads();                        // cur-buf loads done; next-target readers done
    if (kt + 1 < nk) stage(cb ^ 1, (kt + 1) << 5);   // overlaps with compute below
    s16x8 af[4], bfr[NF];
    #pragma unroll
    for (int mt = 0; mt < 4; ++mt) {
      const int m = wy*64 + mt*16 + l15;
      const int r = m >> 1;
      const int cq = (((m & 1) << 2) | quad) ^ (r & 7);
      af[mt] = *(const s16x8*)((const char*)As[cb] + r*128 + cq*16);
    }
    #pragma unroll
    for (int nt = 0; nt < NF; ++nt) {
      const int n = wx*(NTILE/2) + nt*16 + l15;
      const int r = n >> 1;
      const int cq = (((n & 1) << 2) | quad) ^ (r & 7);
      bfr[nt] = *(const s16x8*)((const char*)Bs[cb] + r*128 + cq*16);
    }
    #pragma unroll
    for (int mt = 0; mt < 4; ++mt)
      #pragma unroll
      for (int nt = 0; nt < NF; ++nt)
        acc[mt][nt] = mfma16(af[mt], bfr[nt], acc[mt][nt]);
  }

  #pragma unroll
  for (int nt = 0; nt < NF; ++nt) {
    const int col = n0 + wx*(NTILE/2) + nt*16 + l15;
    float bv = 0.f;
    if constexpr (DO_BIAS) bv = bias[col];
    #pragma unroll
    for (int mt = 0; mt < 4; ++mt) {
      #pragma unroll
      for (int r = 0; r < 4; ++r) {
        const int row = m0 + wy*64 + mt*16 + quad*4 + r;
        float v = acc[mt][nt][r];
        if constexpr (DO_BIAS) v += bv;
        if constexpr (DO_GELU) v = 0.5f*v*(1.0f + erff(v*0.70710678118654752f));
        const size_t idx = (size_t)row*Nn + col;
        if constexpr (OUT_BF16) Cb[idx] = f2b(v);
        else if constexpr (DO_RES) Cf[idx] += v;
        else Cf[idx] = v;
      }
    }
  }
}

// ---------------------------------------------------------------- qk rmsnorm + split + V-transpose
// qkv: [MR][2304] f32 (q|k|v). Out: Qb/Kb [b][h][n][64] bf16, VTb [b][h][d][1024] bf16.
__global__ __launch_bounds__(256) void rms_qkv_kernel(const float* __restrict__ qkv,
    const float* __restrict__ qg, const float* __restrict__ kg,
    bf16* __restrict__ Qb, bf16* __restrict__ Kb, bf16* __restrict__ VTb)
{
  __shared__ float tile[64*68];
  const int nt = blockIdx.x, h = blockIdx.y, b = blockIdx.z;
  const int tid = threadIdx.x;
  const int bh = b*NH + h;
  const size_t rowbase = (size_t)(b*NTOK + nt*64);
  const int r = tid >> 2, pp = tid & 3;

  auto stage = [&](int off) {
    #pragma unroll
    for (int rr = 0; rr < 4; ++rr) {
      const int idx = rr*256 + tid;
      const int rw = idx >> 4, c4 = (idx & 15) << 2;
      float4 val = *(const float4*)(qkv + (rowbase + rw)*2304 + off + c4);
      *(float4*)(&tile[rw*68 + c4]) = val;
    }
  };

  // ---- Q
  stage(h*64);
  __syncthreads();
  {
    float ssq = 0.f;
    #pragma unroll
    for (int i = 0; i < 16; ++i) { float x = tile[r*68 + pp*16 + i]; ssq += x*x; }
    ssq += __shfl_xor(ssq, 1); ssq += __shfl_xor(ssq, 2);
    const float rn = 8.0f / fmaxf(sqrtf(ssq), 1e-12f);
    bf16* orow = Qb + ((size_t)bh*NTOK + nt*64 + r)*64;
    #pragma unroll
    for (int i = 0; i < 16; ++i) { int d = pp*16+i; orow[d] = f2b(tile[r*68+d]*rn*qg[h*64+d]); }
  }
  __syncthreads();
  // ---- K
  stage(768 + h*64);
  __syncthreads();
  {
    float ssq = 0.f;
    #pragma unroll
    for (int i = 0; i < 16; ++i) { float x = tile[r*68 + pp*16 + i]; ssq += x*x; }
    ssq += __shfl_xor(ssq, 1); ssq += __shfl_xor(ssq, 2);
    const float rn = 8.0f / fmaxf(sqrtf(ssq), 1e-12f);
    bf16* orow = Kb + ((size_t)bh*NTOK + nt*64 + r)*64;
    #pragma unroll
    for (int i = 0; i < 16; ++i) { int d = pp*16+i; orow[d] = f2b(tile[r*68+d]*rn*kg[h*64+d]); }
  }
  __syncthreads();
  // ---- V (transposed out: VT[d][token])
  stage(1536 + h*64);
  __syncthreads();
  {
    const int d = tid >> 2;
    bf16* orow = VTb + ((size_t)bh*64 + d)*NTOK + nt*64;
    #pragma unroll
    for (int i = 0; i < 16; ++i) { int n = pp*16 + i; orow[n] = f2b(tile[n*68 + d]); }
  }
}

// ---------------------------------------------------------------- fused MFMA attention
__global__ __launch_bounds__(256) void attn_mfma(const bf16* __restrict__ Qb,
    const bf16* __restrict__ Kb, const bf16* __restrict__ VTb, bf16* __restrict__ Ob,
    const int* __restrict__ ids, const int* __restrict__ lens)
{
  __shared__ bf16 Ps[4][16*72];   // per-wave P tile [m=16][j=64], row stride 72 elems
  __shared__ int  ids_s[NTOK];
  const int qt = blockIdx.x, h = blockIdx.y, b = blockIdx.z;
  const int tid = threadIdx.x;
  const int wid = tid >> 6, lane = tid & 63;
  const int quad = lane >> 4, l15 = lane & 15;
  const int bh = b*NH + h;
  const int q0 = qt*64;
  const int len = lens[b];

  #pragma unroll
  for (int i = 0; i < 4; ++i) ids_s[i*256 + tid] = ids[b*NTOK + i*256 + tid];
  __syncthreads();

  const bf16* qrow = Qb + ((size_t)bh*NTOK + q0 + wid*16 + l15)*64;
  const s16x8 aq0 = *(const s16x8*)(qrow + quad*8);
  const s16x8 aq1 = *(const s16x8*)(qrow + 32 + quad*8);

  int idq[4];
  #pragma unroll
  for (int rr = 0; rr < 4; ++rr) idq[rr] = ids_s[q0 + wid*16 + quad*4 + rr];

  unsigned qm = 0;
  #pragma unroll
  for (int rr = 0; rr < 4; ++rr) qm |= 1u << (idq[rr] & 31);
  #pragma unroll
  for (int o = 32; o >= 1; o >>= 1) qm |= (unsigned)__shfl_xor((int)qm, o);

  f32x4 oacc[4];
  #pragma unroll
  for (int nt = 0; nt < 4; ++nt) oacc[nt] = (f32x4){0.f,0.f,0.f,0.f};
  float mrow[4] = {-3.0e38f,-3.0e38f,-3.0e38f,-3.0e38f};
  float lrow[4] = {0.f,0.f,0.f,0.f};

  const bf16* Kgb = Kb  + (size_t)bh*NTOK*64;
  const bf16* Vgb = VTb + (size_t)bh*64*NTOK;
  bf16* pw = Ps[wid];

  for (int kt = 0; kt < 16; ++kt) {
    const int k0 = kt*64;
    const int idk_l = ids_s[k0 + lane];
    const bool ok = ((k0 + lane) < len) && (((qm >> (idk_l & 31)) & 1u) != 0u);
    if (__ballot(ok) == 0ULL) continue;

    f32x4 sA[4];
    #pragma unroll
    for (int jt = 0; jt < 4; ++jt) {
      const bf16* krow = Kgb + (size_t)(k0 + jt*16 + l15)*64;
      const s16x8 bk0 = *(const s16x8*)(krow + quad*8);
      const s16x8 bk1 = *(const s16x8*)(krow + 32 + quad*8);
      f32x4 s = (f32x4){0.f,0.f,0.f,0.f};
      s = mfma16(aq0, bk0, s);
      s = mfma16(aq1, bk1, s);
      sA[jt] = s;
    }
    #pragma unroll
    for (int jt = 0; jt < 4; ++jt) {
      const int j = k0 + jt*16 + l15;
      const int idk = ids_s[j];
      const bool kvld = j < len;
      #pragma unroll
      for (int rr = 0; rr < 4; ++rr)
        sA[jt][rr] = (kvld && idk == idq[rr]) ? sA[jt][rr] : -3.0e38f;
    }
    float alpha[4], mnew[4];
    #pragma unroll
    for (int rr = 0; rr < 4; ++rr) {
      float mx = fmaxf(fmaxf(sA[0][rr], sA[1][rr]), fmaxf(sA[2][rr], sA[3][rr]));
      mx = fmaxf(mx, __shfl_xor(mx, 1));
      mx = fmaxf(mx, __shfl_xor(mx, 2));
      mx = fmaxf(mx, __shfl_xor(mx, 4));
      mx = fmaxf(mx, __shfl_xor(mx, 8));
      const float mn = fmaxf(mrow[rr], mx);
      mnew[rr] = mn;
      alpha[rr] = expf(mrow[rr] - mn);
      mrow[rr] = mn;
    }
    #pragma unroll
    for (int rr = 0; rr < 4; ++rr) {
      float rs = 0.f;
      #pragma unroll
      for (int jt = 0; jt < 4; ++jt) {
        const float pv = (sA[jt][rr] > -1.0e38f) ? expf(sA[jt][rr] - mnew[rr]) : 0.0f;
        sA[jt][rr] = pv;
        rs += pv;
      }
      rs += __shfl_xor(rs, 1);
      rs += __shfl_xor(rs, 2);
      rs += __shfl_xor(rs, 4);
      rs += __shfl_xor(rs, 8);
      lrow[rr] = lrow[rr]*alpha[rr] + rs;
      #pragma unroll
      for (int nt = 0; nt < 4; ++nt) oacc[nt][rr] *= alpha[rr];
    }
    #pragma unroll
    for (int jt = 0; jt < 4; ++jt)
      #pragma unroll
      for (int rr = 0; rr < 4; ++rr)
        pw[(quad*4+rr)*72 + jt*16 + l15] = f2b(sA[jt][rr]);
    #pragma unroll
    for (int ss = 0; ss < 2; ++ss) {
      const s16x8 ap = *(const s16x8*)(pw + l15*72 + ss*32 + quad*8);
      #pragma unroll
      for (int nt = 0; nt < 4; ++nt) {
        const s16x8 bv = *(const s16x8*)(Vgb + (size_t)(nt*16 + l15)*NTOK + k0 + ss*32 + quad*8);
        oacc[nt] = mfma16(ap, bv, oacc[nt]);
      }
    }
  }

  #pragma unroll
  for (int rr = 0; rr < 4; ++rr) {
    const float inv = lrow[rr] > 0.f ? 1.0f/lrow[rr] : 0.0f;
    const int n = q0 + wid*16 + quad*4 + rr;
    bf16* orow = Ob + ((size_t)b*NTOK + n)*768 + h*64;
    #pragma unroll
    for (int nt = 0; nt < 4; ++nt)
      orow[nt*16 + l15] = f2b(oacc[nt][rr]*inv);
  }
}

// ---------------------------------------------------------------- pooling path
__global__ __launch_bounds__(256) void pool_q_kernel(const float* __restrict__ pool_q,
    const float* __restrict__ pool_ln_g, const float* __restrict__ pWq,
    const float* __restrict__ p_qn_g, float* __restrict__ qp)
{
  __shared__ float xn[768];
  __shared__ float scratch[4];
  __shared__ float qraw[64];
  const int h = blockIdx.x, tid = threadIdx.x;
  float v0 = pool_q[tid], v1 = pool_q[tid+256], v2 = pool_q[tid+512];
  const float s  = block_sum(v0+v1+v2, scratch, tid);
  const float ss = block_sum(v0*v0+v1*v1+v2*v2, scratch, tid);
  const float mu = s*(1.0f/768.0f);
  const float rstd = rsqrtf(ss*(1.0f/768.0f) - mu*mu + 1e-5f);
  xn[tid]     = (v0-mu)*rstd*pool_ln_g[tid];
  xn[tid+256] = (v1-mu)*rstd*pool_ln_g[tid+256];
  xn[tid+512] = (v2-mu)*rstd*pool_ln_g[tid+512];
  __syncthreads();
  const int d = tid >> 2, pp = tid & 3;
  const int col = h*64 + d;
  float acc = 0.f;
  for (int k = pp*192; k < (pp+1)*192; ++k) acc += xn[k]*pWq[(size_t)k*768 + col];
  acc += __shfl_xor(acc, 1); acc += __shfl_xor(acc, 2);
  if (pp == 0) qraw[d] = acc;
  __syncthreads();
  if (tid < 64) {
    const float q = qraw[tid];
    float sq = q*q;
    #pragma unroll
    for (int o = 32; o >= 1; o >>= 1) sq += __shfl_xor(sq, o);
    const float rn = 8.0f / fmaxf(sqrtf(sq), 1e-12f);
    qp[h*64 + tid] = q * rn * p_qn_g[h*64 + tid];
  }
}

__global__ __launch_bounds__(256) void pool_attn_kernel(const float* __restrict__ kvp,
    const float* __restrict__ qp, const float* __restrict__ kg,
    const int* __restrict__ ids, const int* __restrict__ lens, float* __restrict__ pooled)
{
  __shared__ float sp[1024];
  __shared__ float qg_s[64];
  __shared__ float scratch[4];
  __shared__ float outred[4][64];
  const int h = blockIdx.x, img = blockIdx.y, b = blockIdx.z;
  const int tid = threadIdx.x;
  const int len = lens[b];
  if (tid < 64) qg_s[tid] = qp[h*64 + tid] * kg[h*64 + tid];
  __syncthreads();

  float smax = -3.0e38f;
  for (int j = tid; j < 1024; j += 256) {
    float sv = -3.0e38f;
    if (j < len && ids[b*NTOK + j] == img) {
      const float* kr = kvp + (size_t)(b*NTOK + j)*1536 + h*64;
      float ssq = 0.f, dq = 0.f;
      #pragma unroll
      for (int dd = 0; dd < 64; dd += 4) {
        float4 k4 = *(const float4*)(kr + dd);
        ssq += k4.x*k4.x + k4.y*k4.y + k4.z*k4.z + k4.w*k4.w;
        dq  += qg_s[dd]*k4.x + qg_s[dd+1]*k4.y + qg_s[dd+2]*k4.z + qg_s[dd+3]*k4.w;
      }
      const float rn = 8.0f / fmaxf(sqrtf(ssq), 1e-12f);
      sv = dq * rn;
    }
    sp[j] = sv;
    smax = fmaxf(smax, sv);
  }
  const float M = block_max(smax, scratch, tid);
  float lsum = 0.f;
  for (int j = tid; j < 1024; j += 256) {
    const float p = (sp[j] > -1.0e38f) ? expf(sp[j] - M) : 0.0f;
    sp[j] = p;
    lsum += p;
  }
  const float L = block_sum(lsum, scratch, tid);
  const float invL = L > 0.f ? 1.0f / L : 0.0f;

  const int d = tid & 63, jg = tid >> 6;
  float acc = 0.f;
  for (int j = jg; j < 1024; j += 4) {
    const float p = sp[j];
    if (p > 0.f) acc += p * kvp[(size_t)(b*NTOK + j)*1536 + 768 + h*64 + d];
  }
  outred[jg][d] = acc;
  __syncthreads();
  if (tid < 64) {
    const float o = (outred[0][tid] + outred[1][tid] + outred[2][tid] + outred[3][tid]) * invL;
    pooled[((size_t)b*NIMG + img)*768 + h*64 + tid] = o;
  }
}

__global__ __launch_bounds__(256) void pool_out_kernel(const float* __restrict__ pooled,
    const float* __restrict__ pWo, const float* __restrict__ pool_q, float* __restrict__ pooledf)
{
  const int idx = blockIdx.x*256 + threadIdx.x;   // 16*768
  const int r = idx / 768, c = idx % 768;
  float acc = pool_q[c];
  const float* pr = pooled + (size_t)r*768;
  for (int k = 0; k < 768; ++k) acc += pr[k] * pWo[(size_t)k*768 + c];
  pooledf[idx] = acc;
}

__global__ __launch_bounds__(256) void head_kernel(const bf16* __restrict__ hl,
    const float* __restrict__ Wh, float* __restrict__ out)
{
  const int idx = blockIdx.x*256 + threadIdx.x;
  if (idx >= 16*NCLS) return;
  const int r = idx / NCLS, c = idx % NCLS;
  const bf16* hr = hl + (size_t)r*768;
  float acc = 0.f;
  for (int k = 0; k < 768; ++k) acc += b2f(hr[k]) * Wh[(size_t)k*NCLS + c];
  out[idx] = acc;
}

// ---------------------------------------------------------------- host
extern "C" void kernel_launch(void* const* d_in, const int* in_sizes, int n_in,
                              void* d_out, int out_size, void* d_ws, size_t ws_size,
                              hipStream_t stream)
{
  const float* patches    = (const float*)d_in[0];
  const int*   ppos       = (const int*)d_in[1];
  const int*   image_ids  = (const int*)d_in[2];
  const int*   lengths    = (const int*)d_in[3];
  const float* emb_ln_g   = (const float*)d_in[4];
  const float* W_emb      = (const float*)d_in[5];
  const float* b_emb      = (const float*)d_in[6];
  const float* emb_ln2_g  = (const float*)d_in[7];
  const float* pos_h      = (const float*)d_in[8];
  const float* pos_w      = (const float*)d_in[9];
  const float* ln_attn_g  = (const float*)d_in[10];
  const float* Wq         = (const float*)d_in[11];
  const float* Wkv        = (const float*)d_in[12];
  const float* qn_g       = (const float*)d_in[13];
  const float* kn_g       = (const float*)d_in[14];
  const float* Wo         = (const float*)d_in[15];
  const float* ln_ff_g    = (const float*)d_in[16];
  const float* W1         = (const float*)d_in[17];
  const float* b1         = (const float*)d_in[18];
  const float* W2         = (const float*)d_in[19];
  const float* b2v        = (const float*)d_in[20];
  const float* final_ln_g = (const float*)d_in[21];
  const float* pool_q     = (const float*)d_in[22];
  const float* pool_ln_g  = (const float*)d_in[23];
  const float* pWq        = (const float*)d_in[24];
  const float* pWkv       = (const float*)d_in[25];
  const float* p_qn_g     = (const float*)d_in[26];
  const float* p_kn_g     = (const float*)d_in[27];
  const float* pWo        = (const float*)d_in[28];
  const float* head_ln_g  = (const float*)d_in[29];
  const float* W_head     = (const float*)d_in[30];

  char* ws = (char*)d_ws;
  size_t off = 0;
  auto alloc = [&](size_t sz){ size_t r = off; off += (sz + 255) & ~(size_t)255; return r; };

  const size_t o_WembT = alloc((size_t)768*768*2);
  size_t o_QKVT[4], o_WoT[4], o_W1T[4], o_W2T[4];
  for (int l = 0; l < NLAYER; ++l) {
    o_QKVT[l] = alloc((size_t)2304*768*2);
    o_WoT[l]  = alloc((size_t)768*768*2);
    o_W1T[l]  = alloc((size_t)3072*768*2);
    o_W2T[l]  = alloc((size_t)768*3072*2);
  }
  const size_t o_pWkvT = alloc((size_t)1536*768*2);
  const size_t o_x     = alloc((size_t)MR*768*4);
  const size_t o_xn    = alloc((size_t)MR*768*2);
  const size_t o_qkv   = alloc((size_t)MR*2304*4);   // also reused for h (bf16) and pool kv
  const size_t o_Qb    = alloc((size_t)MR*768*2);
  const size_t o_Kb    = alloc((size_t)MR*768*2);
  const size_t o_VT    = alloc((size_t)MR*768*2);
  const size_t o_Ob    = alloc((size_t)MR*768*2);
  const size_t o_qp    = alloc((size_t)768*4);
  const size_t o_pool  = alloc((size_t)16*768*4);
  const size_t o_poolf = alloc((size_t)16*768*4);
  const size_t o_hl    = alloc((size_t)16*768*2);
  if (off > ws_size) return;  // workspace too small: fail visibly (poisoned out)

  float* x    = (float*)(ws + o_x);
  bf16*  xn   = (bf16*)(ws + o_xn);
  float* qkv  = (float*)(ws + o_qkv);
  bf16*  hb   = (bf16*)(ws + o_qkv);   // aliases qkv, used after rms_qkv consumed it
  bf16*  Qb   = (bf16*)(ws + o_Qb);
  bf16*  Kb   = (bf16*)(ws + o_Kb);
  bf16*  VTb  = (bf16*)(ws + o_VT);
  bf16*  Ob   = (bf16*)(ws + o_Ob);
  float* qp   = (float*)(ws + o_qp);
  float* pooled  = (float*)(ws + o_pool);
  float* pooledf = (float*)(ws + o_poolf);
  bf16*  hl   = (bf16*)(ws + o_hl);

  // ---- batched weight transpose + bf16 convert
  TDesc td; int ne = 0, total = 0;
  auto add = [&](const float* s, size_t dofs, int R, int C){
    td.e[ne].src = s;
    td.e[ne].dst = (bf16*)(ws + dofs);
    td.e[ne].R = R; td.e[ne].C = C;
    td.e[ne].tiles = (R/32)*(C/32); td.e[ne].tC = C/32;
    total += td.e[ne].tiles; ++ne;
  };
  add(W_emb, o_WembT, 768, 768);
  for (int l = 0; l < NLAYER; ++l) {
    add(Wq  + (size_t)l*768*768,  o_QKVT[l],                 768, 768);
    add(Wkv + (size_t)l*768*1536, o_QKVT[l] + (size_t)768*768*2, 768, 1536);
    add(Wo  + (size_t)l*768*768,  o_WoT[l],                  768, 768);
    add(W1  + (size_t)l*768*3072, o_W1T[l],                  768, 3072);
    add(W2  + (size_t)l*3072*768, o_W2T[l],                  3072, 768);
  }
  add(pWkv, o_pWkvT, 768, 1536);
  transpose_kernel<<<total, 256, 0, stream>>>(td, ne);

  // ---- embed
  ln768_kernel<<<MR, 256, 0, stream>>>(patches, emb_ln_g, xn);
  gemm_mfma<1,0,0,0,64><<<dim3(12,32), 256, 0, stream>>>(xn, (const bf16*)(ws+o_WembT), b_emb,
                                                         qkv, nullptr, MR, 768, 768);
  ln_pos_kernel<<<MR, 256, 0, stream>>>(qkv, emb_ln2_g, pos_h, pos_w, ppos, x);

  // ---- transformer layers
  for (int l = 0; l < NLAYER; ++l) {
    ln768_kernel<<<MR, 256, 0, stream>>>(x, ln_attn_g + (size_t)l*768, xn);
    gemm_mfma<0,0,0,0,128><<<dim3(18,32), 256, 0, stream>>>(xn, (const bf16*)(ws+o_QKVT[l]), nullptr,
                                                            qkv, nullptr, MR, 2304, 768);
    rms_qkv_kernel<<<dim3(16,NH,NB), 256, 0, stream>>>(qkv, qn_g + (size_t)l*768, kn_g + (size_t)l*768,
                                                       Qb, Kb, VTb);
    attn_mfma<<<dim3(16,NH,NB), 256, 0, stream>>>(Qb, Kb, VTb, Ob, image_ids, lengths);
    // Wo: residual += into x (single writer per element)
    gemm_mfma<0,0,0,1,64><<<dim3(12,32), 256, 0, stream>>>(Ob, (const bf16*)(ws+o_WoT[l]), nullptr,
                                                           x, nullptr, MR, 768, 768);
    ln768_kernel<<<MR, 256, 0, stream>>>(x, ln_ff_g + (size_t)l*768, xn);
    gemm_mfma<1,1,1,0,128><<<dim3(24,32), 256, 0, stream>>>(xn, (const bf16*)(ws+o_W1T[l]), b1 + (size_t)l*3072,
                                                            nullptr, hb, MR, 3072, 768);
    // W2: residual += into x with bias
    gemm_mfma<1,0,0,1,64><<<dim3(12,32), 256, 0, stream>>>(hb, (const bf16*)(ws+o_W2T[l]), b2v + (size_t)l*768,
                                                           x, nullptr, MR, 768, 3072);
  }

  // ---- final LN + pooling + head
  ln768_kernel<<<MR, 256, 0, stream>>>(x, final_ln_g, xn);
  gemm_mfma<0,0,0,0,128><<<dim3(12,32), 256, 0, stream>>>(xn, (const bf16*)(ws+o_pWkvT), nullptr,
                                                          qkv, nullptr, MR, 1536, 768);
  pool_q_kernel<<<NH, 256, 0, stream>>>(pool_q, pool_ln_g, pWq, p_qn_g, qp);
  pool_attn_kernel<<<dim3(NH,NIMG,NB), 256, 0, stream>>>(qkv, qp, p_kn_g, image_ids, lengths, pooled);
  pool_out_kernel<<<48, 256, 0, stream>>>(pooled, pWo, pool_q, pooledf);
  ln768_kernel<<<16, 256, 0, stream>>>(pooledf, head_ln_g, hl);
  head_kernel<<<(16*NCLS + 255)/256, 256, 0, stream>>>(hl, W_head, (float*)d_out);
}

// Round 8
// 1183.902 us; speedup vs baseline: 4.1527x; 1.0481x over previous
//
#include <hip/hip_runtime.h>
#include <hip/hip_bf16.h>
#include <math.h>

using bf16 = __hip_bfloat16;
typedef short s16x8 __attribute__((ext_vector_type(8)));
typedef float f32x4 __attribute__((ext_vector_type(4)));

#define DEVI __device__ __forceinline__

static constexpr int NB    = 4;
static constexpr int NTOK  = 1024;
static constexpr int DIM   = 768;
static constexpr int NH    = 12;
static constexpr int MLPD  = 3072;
static constexpr int NLAYER= 4;
static constexpr int NIMG  = 4;
static constexpr int NCLS  = 1000;
static constexpr int MR    = NB * NTOK;   // 4096 rows

DEVI float b2f(bf16 v){ return __bfloat162float(v); }
DEVI bf16  f2b(float v){ return __float2bfloat16(v); }

DEVI void async16(const void* g, void* l) {
  __builtin_amdgcn_global_load_lds((const __attribute__((address_space(1))) void*)g,
                                   (__attribute__((address_space(3))) void*)l, 16, 0, 0);
}

DEVI f32x4 mfma16(s16x8 a, s16x8 b, f32x4 c) {
  return __builtin_amdgcn_mfma_f32_16x16x32_bf16(a, b, c, 0, 0, 0);
}

DEVI float block_sum(float v, float* scratch, int tid) {
  #pragma unroll
  for (int o = 32; o >= 1; o >>= 1) v += __shfl_xor(v, o);
  __syncthreads();
  if ((tid & 63) == 0) scratch[tid >> 6] = v;
  __syncthreads();
  return scratch[0] + scratch[1] + scratch[2] + scratch[3];
}

DEVI float block_max(float v, float* scratch, int tid) {
  #pragma unroll
  for (int o = 32; o >= 1; o >>= 1) v = fmaxf(v, __shfl_xor(v, o));
  __syncthreads();
  if ((tid & 63) == 0) scratch[tid >> 6] = v;
  __syncthreads();
  return fmaxf(fmaxf(scratch[0], scratch[1]), fmaxf(scratch[2], scratch[3]));
}

// ---------------------------------------------------------------- transpose + f32->bf16 convert
struct bh4 { bf16 a, b, c, d; };
struct TEntry { const float* src; bf16* dst; int R, C, tiles, tC; };
struct TDesc  { TEntry e[22]; };

__global__ __launch_bounds__(256) void transpose_kernel(TDesc D, int nent) {
  int bid = blockIdx.x, ei = 0;
  while (ei < nent - 1 && bid >= D.e[ei].tiles) { bid -= D.e[ei].tiles; ++ei; }
  const TEntry E = D.e[ei];
  const int tr = bid / E.tC, tc = bid % E.tC;
  __shared__ bf16 t[32][33];
  const int tid = threadIdx.x;
  const int lr = tid >> 3, lc = (tid & 7) * 4;
  const float* srow = E.src + (size_t)(tr*32 + lr)*E.C + tc*32 + lc;
  float4 v = *(const float4*)srow;
  t[lr][lc] = f2b(v.x); t[lr][lc+1] = f2b(v.y); t[lr][lc+2] = f2b(v.z); t[lr][lc+3] = f2b(v.w);
  __syncthreads();
  bh4 o;
  o.a = t[lc+0][lr]; o.b = t[lc+1][lr]; o.c = t[lc+2][lr]; o.d = t[lc+3][lr];
  *(bh4*)(E.dst + (size_t)(tc*32 + lr)*E.R + tr*32 + lc) = o;
}

// ---------------------------------------------------------------- LayerNorm (768 cols), f32 in, bf16 out
__global__ __launch_bounds__(256) void ln768_kernel(const float* __restrict__ in,
    const float* __restrict__ g, bf16* __restrict__ out)
{
  __shared__ float scratch[4];
  const int row = blockIdx.x, tid = threadIdx.x;
  const float* p = in + (size_t)row*768;
  const float v0 = p[tid], v1 = p[tid+256], v2 = p[tid+512];
  const float s  = block_sum(v0+v1+v2, scratch, tid);
  const float ss = block_sum(v0*v0+v1*v1+v2*v2, scratch, tid);
  const float mu = s * (1.0f/768.0f);
  const float var = ss * (1.0f/768.0f) - mu*mu;
  const float rstd = rsqrtf(var + 1e-5f);
  bf16* o = out + (size_t)row*768;
  o[tid]     = f2b((v0-mu)*rstd*g[tid]);
  o[tid+256] = f2b((v1-mu)*rstd*g[tid+256]);
  o[tid+512] = f2b((v2-mu)*rstd*g[tid+512]);
}

// LN + positional add (embed stage 2), f32 out
__global__ __launch_bounds__(256) void ln_pos_kernel(const float* __restrict__ in,
    const float* __restrict__ g, const float* __restrict__ pos_h, const float* __restrict__ pos_w,
    const int* __restrict__ ppos, float* __restrict__ out)
{
  __shared__ float scratch[4];
  const int row = blockIdx.x, tid = threadIdx.x;
  const float* p = in + (size_t)row*768;
  const float v0 = p[tid], v1 = p[tid+256], v2 = p[tid+512];
  const float s  = block_sum(v0+v1+v2, scratch, tid);
  const float ss = block_sum(v0*v0+v1*v1+v2*v2, scratch, tid);
  const float mu = s * (1.0f/768.0f);
  const float rstd = rsqrtf(ss*(1.0f/768.0f) - mu*mu + 1e-5f);
  const int p0 = ppos[row*2], p1 = ppos[row*2+1];
  const float* ph = pos_h + (size_t)p0*768;
  const float* pw = pos_w + (size_t)p1*768;
  float* o = out + (size_t)row*768;
  o[tid]     = (v0-mu)*rstd*g[tid]     + ph[tid]     + pw[tid];
  o[tid+256] = (v1-mu)*rstd*g[tid+256] + ph[tid+256] + pw[tid+256];
  o[tid+512] = (v2-mu)*rstd*g[tid+512] + ph[tid+512] + pw[tid+512];
}

// ---------------------------------------------------------------- GEMM (MFMA, XOR-swizzled LDS, double-buffered)
template<int DO_BIAS, int DO_GELU, int OUT_BF16, int DO_RES, int NTILE>
__global__ __launch_bounds__(256)
void gemm_mfma(const bf16* __restrict__ A, const bf16* __restrict__ BT,
               const float* __restrict__ bias, float* __restrict__ Cf,
               bf16* __restrict__ Cb, int M, int Nn, int K)
{
  constexpr int NF = NTILE / 32;            // n-frags per wave (2 or 4)
  __shared__ bf16 As[2][64*64];             // 2 x 8 KB
  __shared__ bf16 Bs[2][(NTILE/2)*64];      // 2 x (4 or 8) KB
  const int tid = threadIdx.x;
  const int wid = tid >> 6, lane = tid & 63;
  const int quad = lane >> 4, l15 = lane & 15;
  const int wy = wid >> 1, wx = wid & 1;
  const int m0 = blockIdx.y * 128, n0 = blockIdx.x * NTILE;
  const int rl = lane >> 3;                 // local LDS row 0..7
  const int cs = lane & 7;                  // slot 0..7

  f32x4 acc[4][NF];
  #pragma unroll
  for (int i = 0; i < 4; ++i)
    #pragma unroll
    for (int j = 0; j < NF; ++j) acc[i][j] = (f32x4){0.f,0.f,0.f,0.f};

  auto stage = [&](int buf, int k0) {
    #pragma unroll
    for (int c = 0; c < 2; ++c) {
      const int rbase = wid*8 + c*32;
      const int r_abs = rbase + rl;
      const int ceff  = cs ^ (r_abs & 7);
      const int mg    = 2*r_abs + (ceff >> 2);
      const int jb    = (ceff & 3) * 16;
      async16((const char*)A + ((size_t)(m0 + mg)*K + k0)*2 + jb, (char*)As[buf] + rbase*128);
    }
    #pragma unroll
    for (int c = 0; c < NTILE/64; ++c) {
      const int rbase = wid*8 + c*32;
      const int r_abs = rbase + rl;
      const int ceff  = cs ^ (r_abs & 7);
      const int ng    = 2*r_abs + (ceff >> 2);
      const int jb    = (ceff & 3) * 16;
      async16((const char*)BT + ((size_t)(n0 + ng)*K + k0)*2 + jb, (char*)Bs[buf] + rbase*128);
    }
  };

  const int nk = K >> 5;
  stage(0, 0);
  for (int kt = 0; kt < nk; ++kt) {
    const int cb = kt & 1;
    __syncthreads();                        // cur-buf loads done; next-target readers done
    if (kt + 1 < nk) stage(cb ^ 1, (kt + 1) << 5);   // overlaps with compute below
    s16x8 af[4], bfr[NF];
    #pragma unroll
    for (int mt = 0; mt < 4; ++mt) {
      const int m = wy*64 + mt*16 + l15;
      const int r = m >> 1;
      const int cq = (((m & 1) << 2) | quad) ^ (r & 7);
      af[mt] = *(const s16x8*)((const char*)As[cb] + r*128 + cq*16);
    }
    #pragma unroll
    for (int nt = 0; nt < NF; ++nt) {
      const int n = wx*(NTILE/2) + nt*16 + l15;
      const int r = n >> 1;
      const int cq = (((n & 1) << 2) | quad) ^ (r & 7);
      bfr[nt] = *(const s16x8*)((const char*)Bs[cb] + r*128 + cq*16);
    }
    #pragma unroll
    for (int mt = 0; mt < 4; ++mt)
      #pragma unroll
      for (int nt = 0; nt < NF; ++nt)
        acc[mt][nt] = mfma16(af[mt], bfr[nt], acc[mt][nt]);
  }

  #pragma unroll
  for (int nt = 0; nt < NF; ++nt) {
    const int col = n0 + wx*(NTILE/2) + nt*16 + l15;
    float bv = 0.f;
    if constexpr (DO_BIAS) bv = bias[col];
    #pragma unroll
    for (int mt = 0; mt < 4; ++mt) {
      #pragma unroll
      for (int r = 0; r < 4; ++r) {
        const int row = m0 + wy*64 + mt*16 + quad*4 + r;
        float v = acc[mt][nt][r];
        if constexpr (DO_BIAS) v += bv;
        if constexpr (DO_GELU) v = 0.5f*v*(1.0f + erff(v*0.70710678118654752f));
        const size_t idx = (size_t)row*Nn + col;
        if constexpr (OUT_BF16) Cb[idx] = f2b(v);
        else if constexpr (DO_RES) Cf[idx] += v;
        else Cf[idx] = v;
      }
    }
  }
}

// ---------------------------------------------------------------- small-M GEMM (M=16, K=768)
// out[16][Nn] = X[16][768] @ W[768][Nn] (+ bias). Threads: 64 cols x 4 k-groups;
// each thread: 192 k-iters, W load amortized over 16 row-FMAs (16-way ILP hides
// L2 latency); 4-way LDS reduce. Replaces the serial-dot pool_out/head kernels.
template<int IN_BF16, int DO_BIAS>
__global__ __launch_bounds__(256) void smallm_gemm(const void* __restrict__ Xv,
    const float* __restrict__ W, const float* __restrict__ bias,
    float* __restrict__ out, int Nn)
{
  __shared__ float Xs[16*768];
  __shared__ float red[4][16][64];
  const int tid = threadIdx.x;
  if constexpr (IN_BF16) {
    const bf16* X = (const bf16*)Xv;
    for (int i = tid; i < 16*768; i += 256) Xs[i] = b2f(X[i]);
  } else {
    const float* X = (const float*)Xv;
    for (int i = tid; i < 16*768; i += 256) Xs[i] = X[i];
  }
  __syncthreads();
  const int cl = tid & 63, kg = tid >> 6;
  const int c = blockIdx.x*64 + cl;
  float acc[16];
  #pragma unroll
  for (int r = 0; r < 16; ++r) acc[r] = 0.f;
  if (c < Nn) {
    const int k0 = kg*192;
    #pragma unroll 4
    for (int k = k0; k < k0 + 192; ++k) {
      const float w = W[(size_t)k*Nn + c];
      #pragma unroll
      for (int r = 0; r < 16; ++r) acc[r] += Xs[r*768 + k] * w;
    }
  }
  #pragma unroll
  for (int r = 0; r < 16; ++r) red[kg][r][cl] = acc[r];
  __syncthreads();
  if (kg == 0 && c < Nn) {
    #pragma unroll
    for (int r = 0; r < 16; ++r) {
      float v = red[0][r][cl] + red[1][r][cl] + red[2][r][cl] + red[3][r][cl];
      if constexpr (DO_BIAS) v += bias[c];
      out[(size_t)r*Nn + c] = v;
    }
  }
}

// ---------------------------------------------------------------- qk rmsnorm + split + V-transpose
// qkv: [MR][2304] f32 (q|k|v). Out: Qb/Kb [b][h][n][64] bf16, VTb [b][h][d][1024] bf16.
__global__ __launch_bounds__(256) void rms_qkv_kernel(const float* __restrict__ qkv,
    const float* __restrict__ qg, const float* __restrict__ kg,
    bf16* __restrict__ Qb, bf16* __restrict__ Kb, bf16* __restrict__ VTb)
{
  __shared__ float tile[64*68];
  const int nt = blockIdx.x, h = blockIdx.y, b = blockIdx.z;
  const int tid = threadIdx.x;
  const int bh = b*NH + h;
  const size_t rowbase = (size_t)(b*NTOK + nt*64);
  const int r = tid >> 2, pp = tid & 3;

  auto stage = [&](int off) {
    #pragma unroll
    for (int rr = 0; rr < 4; ++rr) {
      const int idx = rr*256 + tid;
      const int rw = idx >> 4, c4 = (idx & 15) << 2;
      float4 val = *(const float4*)(qkv + (rowbase + rw)*2304 + off + c4);
      *(float4*)(&tile[rw*68 + c4]) = val;
    }
  };

  // ---- Q
  stage(h*64);
  __syncthreads();
  {
    float ssq = 0.f;
    #pragma unroll
    for (int i = 0; i < 16; ++i) { float x = tile[r*68 + pp*16 + i]; ssq += x*x; }
    ssq += __shfl_xor(ssq, 1); ssq += __shfl_xor(ssq, 2);
    const float rn = 8.0f / fmaxf(sqrtf(ssq), 1e-12f);
    bf16* orow = Qb + ((size_t)bh*NTOK + nt*64 + r)*64;
    #pragma unroll
    for (int i = 0; i < 16; ++i) { int d = pp*16+i; orow[d] = f2b(tile[r*68+d]*rn*qg[h*64+d]); }
  }
  __syncthreads();
  // ---- K
  stage(768 + h*64);
  __syncthreads();
  {
    float ssq = 0.f;
    #pragma unroll
    for (int i = 0; i < 16; ++i) { float x = tile[r*68 + pp*16 + i]; ssq += x*x; }
    ssq += __shfl_xor(ssq, 1); ssq += __shfl_xor(ssq, 2);
    const float rn = 8.0f / fmaxf(sqrtf(ssq), 1e-12f);
    bf16* orow = Kb + ((size_t)bh*NTOK + nt*64 + r)*64;
    #pragma unroll
    for (int i = 0; i < 16; ++i) { int d = pp*16+i; orow[d] = f2b(tile[r*68+d]*rn*kg[h*64+d]); }
  }
  __syncthreads();
  // ---- V (transposed out: VT[d][token])
  stage(1536 + h*64);
  __syncthreads();
  {
    const int d = tid >> 2;
    bf16* orow = VTb + ((size_t)bh*64 + d)*NTOK + nt*64;
    #pragma unroll
    for (int i = 0; i < 16; ++i) { int n = pp*16 + i; orow[n] = f2b(tile[n*68 + d]); }
  }
}

// ---------------------------------------------------------------- fused MFMA attention
__global__ __launch_bounds__(256) void attn_mfma(const bf16* __restrict__ Qb,
    const bf16* __restrict__ Kb, const bf16* __restrict__ VTb, bf16* __restrict__ Ob,
    const int* __restrict__ ids, const int* __restrict__ lens)
{
  __shared__ bf16 Ps[4][16*72];   // per-wave P tile [m=16][j=64], row stride 72 elems
  __shared__ int  ids_s[NTOK];
  const int qt = blockIdx.x, h = blockIdx.y, b = blockIdx.z;
  const int tid = threadIdx.x;
  const int wid = tid >> 6, lane = tid & 63;
  const int quad = lane >> 4, l15 = lane & 15;
  const int bh = b*NH + h;
  const int q0 = qt*64;
  const int len = lens[b];

  #pragma unroll
  for (int i = 0; i < 4; ++i) ids_s[i*256 + tid] = ids[b*NTOK + i*256 + tid];
  __syncthreads();

  const bf16* qrow = Qb + ((size_t)bh*NTOK + q0 + wid*16 + l15)*64;
  const s16x8 aq0 = *(const s16x8*)(qrow + quad*8);
  const s16x8 aq1 = *(const s16x8*)(qrow + 32 + quad*8);

  int idq[4];
  #pragma unroll
  for (int rr = 0; rr < 4; ++rr) idq[rr] = ids_s[q0 + wid*16 + quad*4 + rr];

  unsigned qm = 0;
  #pragma unroll
  for (int rr = 0; rr < 4; ++rr) qm |= 1u << (idq[rr] & 31);
  #pragma unroll
  for (int o = 32; o >= 1; o >>= 1) qm |= (unsigned)__shfl_xor((int)qm, o);

  f32x4 oacc[4];
  #pragma unroll
  for (int nt = 0; nt < 4; ++nt) oacc[nt] = (f32x4){0.f,0.f,0.f,0.f};
  float mrow[4] = {-3.0e38f,-3.0e38f,-3.0e38f,-3.0e38f};
  float lrow[4] = {0.f,0.f,0.f,0.f};

  const bf16* Kgb = Kb  + (size_t)bh*NTOK*64;
  const bf16* Vgb = VTb + (size_t)bh*64*NTOK;
  bf16* pw = Ps[wid];

  for (int kt = 0; kt < 16; ++kt) {
    const int k0 = kt*64;
    const int idk_l = ids_s[k0 + lane];
    const bool ok = ((k0 + lane) < len) && (((qm >> (idk_l & 31)) & 1u) != 0u);
    if (__ballot(ok) == 0ULL) continue;

    f32x4 sA[4];
    #pragma unroll
    for (int jt = 0; jt < 4; ++jt) {
      const bf16* krow = Kgb + (size_t)(k0 + jt*16 + l15)*64;
      const s16x8 bk0 = *(const s16x8*)(krow + quad*8);
      const s16x8 bk1 = *(const s16x8*)(krow + 32 + quad*8);
      f32x4 s = (f32x4){0.f,0.f,0.f,0.f};
      s = mfma16(aq0, bk0, s);
      s = mfma16(aq1, bk1, s);
      sA[jt] = s;
    }
    #pragma unroll
    for (int jt = 0; jt < 4; ++jt) {
      const int j = k0 + jt*16 + l15;
      const int idk = ids_s[j];
      const bool kvld = j < len;
      #pragma unroll
      for (int rr = 0; rr < 4; ++rr)
        sA[jt][rr] = (kvld && idk == idq[rr]) ? sA[jt][rr] : -3.0e38f;
    }
    float alpha[4], mnew[4];
    #pragma unroll
    for (int rr = 0; rr < 4; ++rr) {
      float mx = fmaxf(fmaxf(sA[0][rr], sA[1][rr]), fmaxf(sA[2][rr], sA[3][rr]));
      mx = fmaxf(mx, __shfl_xor(mx, 1));
      mx = fmaxf(mx, __shfl_xor(mx, 2));
      mx = fmaxf(mx, __shfl_xor(mx, 4));
      mx = fmaxf(mx, __shfl_xor(mx, 8));
      const float mn = fmaxf(mrow[rr], mx);
      mnew[rr] = mn;
      alpha[rr] = expf(mrow[rr] - mn);
      mrow[rr] = mn;
    }
    #pragma unroll
    for (int rr = 0; rr < 4; ++rr) {
      float rs = 0.f;
      #pragma unroll
      for (int jt = 0; jt < 4; ++jt) {
        const float pv = (sA[jt][rr] > -1.0e38f) ? expf(sA[jt][rr] - mnew[rr]) : 0.0f;
        sA[jt][rr] = pv;
        rs += pv;
      }
      rs += __shfl_xor(rs, 1);
      rs += __shfl_xor(rs, 2);
      rs += __shfl_xor(rs, 4);
      rs += __shfl_xor(rs, 8);
      lrow[rr] = lrow[rr]*alpha[rr] + rs;
      #pragma unroll
      for (int nt = 0; nt < 4; ++nt) oacc[nt][rr] *= alpha[rr];
    }
    #pragma unroll
    for (int jt = 0; jt < 4; ++jt)
      #pragma unroll
      for (int rr = 0; rr < 4; ++rr)
        pw[(quad*4+rr)*72 + jt*16 + l15] = f2b(sA[jt][rr]);
    #pragma unroll
    for (int ss = 0; ss < 2; ++ss) {
      const s16x8 ap = *(const s16x8*)(pw + l15*72 + ss*32 + quad*8);
      #pragma unroll
      for (int nt = 0; nt < 4; ++nt) {
        const s16x8 bv = *(const s16x8*)(Vgb + (size_t)(nt*16 + l15)*NTOK + k0 + ss*32 + quad*8);
        oacc[nt] = mfma16(ap, bv, oacc[nt]);
      }
    }
  }

  #pragma unroll
  for (int rr = 0; rr < 4; ++rr) {
    const float inv = lrow[rr] > 0.f ? 1.0f/lrow[rr] : 0.0f;
    const int n = q0 + wid*16 + quad*4 + rr;
    bf16* orow = Ob + ((size_t)b*NTOK + n)*768 + h*64;
    #pragma unroll
    for (int nt = 0; nt < 4; ++nt)
      orow[nt*16 + l15] = f2b(oacc[nt][rr]*inv);
  }
}

// ---------------------------------------------------------------- pooling path
__global__ __launch_bounds__(256) void pool_q_kernel(const float* __restrict__ pool_q,
    const float* __restrict__ pool_ln_g, const float* __restrict__ pWq,
    const float* __restrict__ p_qn_g, float* __restrict__ qp)
{
  __shared__ float xn[768];
  __shared__ float scratch[4];
  __shared__ float qraw[64];
  const int h = blockIdx.x, tid = threadIdx.x;
  float v0 = pool_q[tid], v1 = pool_q[tid+256], v2 = pool_q[tid+512];
  const float s  = block_sum(v0+v1+v2, scratch, tid);
  const float ss = block_sum(v0*v0+v1*v1+v2*v2, scratch, tid);
  const float mu = s*(1.0f/768.0f);
  const float rstd = rsqrtf(ss*(1.0f/768.0f) - mu*mu + 1e-5f);
  xn[tid]     = (v0-mu)*rstd*pool_ln_g[tid];
  xn[tid+256] = (v1-mu)*rstd*pool_ln_g[tid+256];
  xn[tid+512] = (v2-mu)*rstd*pool_ln_g[tid+512];
  __syncthreads();
  const int d = tid >> 2, pp = tid & 3;
  const int col = h*64 + d;
  float acc = 0.f;
  for (int k = pp*192; k < (pp+1)*192; ++k) acc += xn[k]*pWq[(size_t)k*768 + col];
  acc += __shfl_xor(acc, 1); acc += __shfl_xor(acc, 2);
  if (pp == 0) qraw[d] = acc;
  __syncthreads();
  if (tid < 64) {
    const float q = qraw[tid];
    float sq = q*q;
    #pragma unroll
    for (int o = 32; o >= 1; o >>= 1) sq += __shfl_xor(sq, o);
    const float rn = 8.0f / fmaxf(sqrtf(sq), 1e-12f);
    qp[h*64 + tid] = q * rn * p_qn_g[h*64 + tid];
  }
}

__global__ __launch_bounds__(256) void pool_attn_kernel(const float* __restrict__ kvp,
    const float* __restrict__ qp, const float* __restrict__ kg,
    const int* __restrict__ ids, const int* __restrict__ lens, float* __restrict__ pooled)
{
  __shared__ float sp[1024];
  __shared__ float qg_s[64];
  __shared__ float scratch[4];
  __shared__ float outred[4][64];
  const int h = blockIdx.x, img = blockIdx.y, b = blockIdx.z;
  const int tid = threadIdx.x;
  const int len = lens[b];
  if (tid < 64) qg_s[tid] = qp[h*64 + tid] * kg[h*64 + tid];
  __syncthreads();

  float smax = -3.0e38f;
  for (int j = tid; j < 1024; j += 256) {
    float sv = -3.0e38f;
    if (j < len && ids[b*NTOK + j] == img) {
      const float* kr = kvp + (size_t)(b*NTOK + j)*1536 + h*64;
      float ssq = 0.f, dq = 0.f;
      #pragma unroll
      for (int dd = 0; dd < 64; dd += 4) {
        float4 k4 = *(const float4*)(kr + dd);
        ssq += k4.x*k4.x + k4.y*k4.y + k4.z*k4.z + k4.w*k4.w;
        dq  += qg_s[dd]*k4.x + qg_s[dd+1]*k4.y + qg_s[dd+2]*k4.z + qg_s[dd+3]*k4.w;
      }
      const float rn = 8.0f / fmaxf(sqrtf(ssq), 1e-12f);
      sv = dq * rn;
    }
    sp[j] = sv;
    smax = fmaxf(smax, sv);
  }
  const float M = block_max(smax, scratch, tid);
  float lsum = 0.f;
  for (int j = tid; j < 1024; j += 256) {
    const float p = (sp[j] > -1.0e38f) ? expf(sp[j] - M) : 0.0f;
    sp[j] = p;
    lsum += p;
  }
  const float L = block_sum(lsum, scratch, tid);
  const float invL = L > 0.f ? 1.0f / L : 0.0f;

  const int d = tid & 63, jg = tid >> 6;
  float acc = 0.f;
  for (int j = jg; j < 1024; j += 4) {
    const float p = sp[j];
    if (p > 0.f) acc += p * kvp[(size_t)(b*NTOK + j)*1536 + 768 + h*64 + d];
  }
  outred[jg][d] = acc;
  __syncthreads();
  if (tid < 64) {
    const float o = (outred[0][tid] + outred[1][tid] + outred[2][tid] + outred[3][tid]) * invL;
    pooled[((size_t)b*NIMG + img)*768 + h*64 + tid] = o;
  }
}

// ---------------------------------------------------------------- host
extern "C" void kernel_launch(void* const* d_in, const int* in_sizes, int n_in,
                              void* d_out, int out_size, void* d_ws, size_t ws_size,
                              hipStream_t stream)
{
  const float* patches    = (const float*)d_in[0];
  const int*   ppos       = (const int*)d_in[1];
  const int*   image_ids  = (const int*)d_in[2];
  const int*   lengths    = (const int*)d_in[3];
  const float* emb_ln_g   = (const float*)d_in[4];
  const float* W_emb      = (const float*)d_in[5];
  const float* b_emb      = (const float*)d_in[6];
  const float* emb_ln2_g  = (const float*)d_in[7];
  const float* pos_h      = (const float*)d_in[8];
  const float* pos_w      = (const float*)d_in[9];
  const float* ln_attn_g  = (const float*)d_in[10];
  const float* Wq         = (const float*)d_in[11];
  const float* Wkv        = (const float*)d_in[12];
  const float* qn_g       = (const float*)d_in[13];
  const float* kn_g       = (const float*)d_in[14];
  const float* Wo         = (const float*)d_in[15];
  const float* ln_ff_g    = (const float*)d_in[16];
  const float* W1         = (const float*)d_in[17];
  const float* b1         = (const float*)d_in[18];
  const float* W2         = (const float*)d_in[19];
  const float* b2v        = (const float*)d_in[20];
  const float* final_ln_g = (const float*)d_in[21];
  const float* pool_q     = (const float*)d_in[22];
  const float* pool_ln_g  = (const float*)d_in[23];
  const float* pWq        = (const float*)d_in[24];
  const float* pWkv       = (const float*)d_in[25];
  const float* p_qn_g     = (const float*)d_in[26];
  const float* p_kn_g     = (const float*)d_in[27];
  const float* pWo        = (const float*)d_in[28];
  const float* head_ln_g  = (const float*)d_in[29];
  const float* W_head     = (const float*)d_in[30];

  char* ws = (char*)d_ws;
  size_t off = 0;
  auto alloc = [&](size_t sz){ size_t r = off; off += (sz + 255) & ~(size_t)255; return r; };

  const size_t o_WembT = alloc((size_t)768*768*2);
  size_t o_QKVT[4], o_WoT[4], o_W1T[4], o_W2T[4];
  for (int l = 0; l < NLAYER; ++l) {
    o_QKVT[l] = alloc((size_t)2304*768*2);
    o_WoT[l]  = alloc((size_t)768*768*2);
    o_W1T[l]  = alloc((size_t)3072*768*2);
    o_W2T[l]  = alloc((size_t)768*3072*2);
  }
  const size_t o_pWkvT = alloc((size_t)1536*768*2);
  const size_t o_x     = alloc((size_t)MR*768*4);
  const size_t o_xn    = alloc((size_t)MR*768*2);
  const size_t o_qkv   = alloc((size_t)MR*2304*4);   // also reused for h (bf16) and pool kv
  const size_t o_Qb    = alloc((size_t)MR*768*2);
  const size_t o_Kb    = alloc((size_t)MR*768*2);
  const size_t o_VT    = alloc((size_t)MR*768*2);
  const size_t o_Ob    = alloc((size_t)MR*768*2);
  const size_t o_qp    = alloc((size_t)768*4);
  const size_t o_pool  = alloc((size_t)16*768*4);
  const size_t o_poolf = alloc((size_t)16*768*4);
  const size_t o_hl    = alloc((size_t)16*768*2);
  if (off > ws_size) return;  // workspace too small: fail visibly (poisoned out)

  float* x    = (float*)(ws + o_x);
  bf16*  xn   = (bf16*)(ws + o_xn);
  float* qkv  = (float*)(ws + o_qkv);
  bf16*  hb   = (bf16*)(ws + o_qkv);   // aliases qkv, used after rms_qkv consumed it
  bf16*  Qb   = (bf16*)(ws + o_Qb);
  bf16*  Kb   = (bf16*)(ws + o_Kb);
  bf16*  VTb  = (bf16*)(ws + o_VT);
  bf16*  Ob   = (bf16*)(ws + o_Ob);
  float* qp   = (float*)(ws + o_qp);
  float* pooled  = (float*)(ws + o_pool);
  float* pooledf = (float*)(ws + o_poolf);
  bf16*  hl   = (bf16*)(ws + o_hl);

  // ---- batched weight transpose + bf16 convert
  TDesc td; int ne = 0, total = 0;
  auto add = [&](const float* s, size_t dofs, int R, int C){
    td.e[ne].src = s;
    td.e[ne].dst = (bf16*)(ws + dofs);
    td.e[ne].R = R; td.e[ne].C = C;
    td.e[ne].tiles = (R/32)*(C/32); td.e[ne].tC = C/32;
    total += td.e[ne].tiles; ++ne;
  };
  add(W_emb, o_WembT, 768, 768);
  for (int l = 0; l < NLAYER; ++l) {
    add(Wq  + (size_t)l*768*768,  o_QKVT[l],                 768, 768);
    add(Wkv + (size_t)l*768*1536, o_QKVT[l] + (size_t)768*768*2, 768, 1536);
    add(Wo  + (size_t)l*768*768,  o_WoT[l],                  768, 768);
    add(W1  + (size_t)l*768*3072, o_W1T[l],                  768, 3072);
    add(W2  + (size_t)l*3072*768, o_W2T[l],                  3072, 768);
  }
  add(pWkv, o_pWkvT, 768, 1536);
  transpose_kernel<<<total, 256, 0, stream>>>(td, ne);

  // ---- embed
  ln768_kernel<<<MR, 256, 0, stream>>>(patches, emb_ln_g, xn);
  gemm_mfma<1,0,0,0,64><<<dim3(12,32), 256, 0, stream>>>(xn, (const bf16*)(ws+o_WembT), b_emb,
                                                         qkv, nullptr, MR, 768, 768);
  ln_pos_kernel<<<MR, 256, 0, stream>>>(qkv, emb_ln2_g, pos_h, pos_w, ppos, x);

  // ---- transformer layers
  for (int l = 0; l < NLAYER; ++l) {
    ln768_kernel<<<MR, 256, 0, stream>>>(x, ln_attn_g + (size_t)l*768, xn);
    gemm_mfma<0,0,0,0,128><<<dim3(18,32), 256, 0, stream>>>(xn, (const bf16*)(ws+o_QKVT[l]), nullptr,
                                                            qkv, nullptr, MR, 2304, 768);
    rms_qkv_kernel<<<dim3(16,NH,NB), 256, 0, stream>>>(qkv, qn_g + (size_t)l*768, kn_g + (size_t)l*768,
                                                       Qb, Kb, VTb);
    attn_mfma<<<dim3(16,NH,NB), 256, 0, stream>>>(Qb, Kb, VTb, Ob, image_ids, lengths);
    // Wo: residual += into x (single writer per element)
    gemm_mfma<0,0,0,1,64><<<dim3(12,32), 256, 0, stream>>>(Ob, (const bf16*)(ws+o_WoT[l]), nullptr,
                                                           x, nullptr, MR, 768, 768);
    ln768_kernel<<<MR, 256, 0, stream>>>(x, ln_ff_g + (size_t)l*768, xn);
    gemm_mfma<1,1,1,0,128><<<dim3(24,32), 256, 0, stream>>>(xn, (const bf16*)(ws+o_W1T[l]), b1 + (size_t)l*3072,
                                                            nullptr, hb, MR, 3072, 768);
    // W2: residual += into x with bias
    gemm_mfma<1,0,0,1,64><<<dim3(12,32), 256, 0, stream>>>(hb, (const bf16*)(ws+o_W2T[l]), b2v + (size_t)l*768,
                                                           x, nullptr, MR, 768, 3072);
  }

  // ---- final LN + pooling + head
  ln768_kernel<<<MR, 256, 0, stream>>>(x, final_ln_g, xn);
  gemm_mfma<0,0,0,0,128><<<dim3(12,32), 256, 0, stream>>>(xn, (const bf16*)(ws+o_pWkvT), nullptr,
                                                          qkv, nullptr, MR, 1536, 768);
  pool_q_kernel<<<NH, 256, 0, stream>>>(pool_q, pool_ln_g, pWq, p_qn_g, qp);
  pool_attn_kernel<<<dim3(NH,NIMG,NB), 256, 0, stream>>>(qkv, qp, p_kn_g, image_ids, lengths, pooled);
  // pooled_final = pooled @ pWo + pool_q (k-parallel small-M GEMM)
  smallm_gemm<0,1><<<12, 256, 0, stream>>>(pooled, pWo, pool_q, pooledf, 768);
  ln768_kernel<<<16, 256, 0, stream>>>(pooledf, head_ln_g, hl);
  // out = LN(pooledf) @ W_head
  smallm_gemm<1,0><<<16, 256, 0, stream>>>(hl, W_head, nullptr, (float*)d_out, NCLS);
}